// Round 14
// baseline (2745.136 us; speedup 1.0000x reference)
//
#include <hip/hip_runtime.h>
#include <math.h>

// FWI forward: 10 shots, 1000 steps, padded grid 130x160 (NBC=30).
// R14 = R12 structure with two reversions/simplifications:
//  - p0 FULLY in registers (p0r[11]; P0g LDS buffer deleted). R12 measured
//    VGPR=88 (40 free) while paying 4 b128/thread-step for P0g + conflicts.
//  - scalar cellq (R13 lesson: v_pk_*_f32 asm gave no VALU-time gain on
//    gfx950 and added operand-move overhead; elementwise scalar is best).
// Keeps: 3 coef streams with NEGATED T2 (q = t1*c + t2n*p0 + al*lap, one op
// fewer), q-lag in-place pA update, receivers stored from registers,
// zlim = min(130-z0, RH), 2 barriers/step.

#define SROW 168                 // Ps row stride; col = x + 4
#define PSZ (136 * SROW)         // stored rows -2..133
#define RH 11                    // rows per thread
#define DTf 0.0008f
#define C2f 1.3333333333333333f  // 4/3
#define C3f (-0.08333333333333333f) // -1/12

#define LD4(arr, i) (*reinterpret_cast<const float4*>(&(arr)[i]))
#define LD2(arr, i) (*reinterpret_cast<const float2*>(&(arr)[i]))
#define ST4(arr, i, v) (*reinterpret_cast<float4*>(&(arr)[i]) = (v))

// ---------- setup 1: velmin reduction, Ricker wavelet, source amplitudes ----------
__global__ __launch_bounds__(1024) void fwi_setup1(const float* __restrict__ v,
                                                   float* __restrict__ ws) {
    int tid = threadIdx.x;
    float m = 3.402823466e38f;
    for (int i = tid; i < 7000; i += 1024) m = fminf(m, v[i]);
    #pragma unroll
    for (int off = 32; off > 0; off >>= 1) m = fminf(m, __shfl_down(m, off, 64));
    __shared__ float red[16];
    if ((tid & 63) == 0) red[tid >> 6] = m;
    __syncthreads();
    if (tid == 0) {
        float mm = red[0];
        for (int i = 1; i < 16; ++i) mm = fminf(mm, red[i]);
        ws[1010] = mm * 1000.0f + 3000.0f;   // denormalized velmin
    }
    // Ricker wavelet: nw=111, nc=55, f*dt*pi = 0.06283185307179587
    if (tid < 1000) {
        float w = 0.0f;
        if (tid < 111) {
            float a = (float)(55 - tid) * 0.06283185307179587f;
            float b = a * a;
            w = (1.0f - 2.0f * b) * expf(-b);
        }
        ws[tid] = w;
    }
    // src_amp[l] = ((v[1][11l]*1000+3000)*DT)^2
    if (tid >= 1000 && tid < 1010) {
        int l = tid - 1000;
        float vd = v[100 + 11 * l] * 1000.0f + 3000.0f;
        float bdt = vd * DTf;
        ws[tid] = bdt * bdt;
    }
}

// ---------- setup 2: per-cell constants AL, T1, T2n(= kdt-1); 132-row padded ----------
__global__ __launch_bounds__(256) void fwi_setup2(const float* __restrict__ v,
                                                  const float* __restrict__ ws,
                                                  float* __restrict__ AL,
                                                  float* __restrict__ T1,
                                                  float* __restrict__ T2) {
    int c = blockIdx.x * 256 + threadIdx.x;
    if (c >= 132 * 160) return;
    if (c >= 130 * 160) { AL[c] = 0.0f; T1[c] = 0.0f; T2[c] = 0.0f; return; }
    float velmin = ws[1010];
    int z = c / 160;
    int x = c - z * 160;
    int iz = min(max(z - 30, 0), 69);
    int ix = min(max(x - 30, 0), 99);
    float vd = v[iz * 100 + ix] * 1000.0f + 3000.0f;
    float tt = vd * DTf / 10.0f;       // v*DT/DX
    float al = tt * tt;                // alpha
    int qx = max(29 - x, x - 130);
    int qz = max(29 - z, z - 100);
    int q = (qx >= 0) ? qx : qz;
    float kdt = 0.0f;
    if (q >= 0) {
        float kap3 = 3.0f * velmin * 16.118095650958319f / 580.0f; // 3*velmin*ln(1e7)/(2*290)
        float r = (float)q * (10.0f / 290.0f);
        kdt = kap3 * (r * r) * DTf;
    }
    AL[c] = al;
    T1[c] = 2.0f - 5.0f * al - kdt;    // temp1
    T2[c] = kdt - 1.0f;                // NEGATED temp2: t1*c + t2n*p0 == t1*c - t2*p0
}

static __device__ __forceinline__ float cellq(float l2, float l1, float cc, float r1, float r2,
                                              float u1, float u2, float d1, float d2,
                                              float al, float t1, float t2n, float p0) {
    float lap = C2f * ((l1 + r1) + (u1 + d1)) + C3f * ((l2 + r2) + (u2 + d2));
    return (t1 * cc + t2n * p0) + al * lap;
}

// ---------- main: one block per shot, 1000 steps ----------
__global__ __launch_bounds__(512) void fwi_main(const float4* __restrict__ AL4,
                                                const float4* __restrict__ T14,
                                                const float4* __restrict__ T24,
                                                const float* __restrict__ ws,
                                                float* __restrict__ out) {
    __shared__ float Ps[PSZ];      // p1 mirror, haloed (91,392 B)
    __shared__ float Wv[128];      // Ricker wavelet (nonzero only t < 111)
    const int tid = threadIdx.x;
    const int shot = blockIdx.x;

    for (int i = tid; i < PSZ; i += 512) Ps[i] = 0.0f;
    if (tid < 128) Wv[tid] = (tid < 111) ? ws[tid] : 0.0f;

    const int g  = tid / 40;            // z-group 0..11 active, >=12 idle
    const int qx = tid - g * 40;        // x-quad 0..39, cells x0 = 4*qx
    const int z0 = g * RH;
    const bool act = (g < 12);
    const float amp = ws[1000 + shot];
    const int xs = 30 + 11 * shot;      // source x (z=31 -> g=2, r=9)
    const bool isrc = act && (g == 2) && (qx == (xs >> 2));
    const int ls = xs & 3;
    const int pc0 = (z0 + 2) * SROW + 4 * qx + 4;  // Ps index of row z0 quad
    const int cb0 = z0 * 40 + qx;                  // coefficient quad index
    const int zlim = min(130 - z0, RH);            // g<11: 11, g==11: 9
    const bool grec = act && (g == 2);             // this thread's r==9 is z=31
    const int xr0 = 4 * qx - 30;                   // receiver index of lane j=0

    float4 pA[RH];                      // p1, morphs into p_new via q-lag
    float4 p0r[RH];                     // p0, all rows in registers
    #pragma unroll
    for (int r = 0; r < RH; ++r) {
        pA[r] = make_float4(0.f, 0.f, 0.f, 0.f);
        p0r[r] = make_float4(0.f, 0.f, 0.f, 0.f);
    }
    __syncthreads();

    for (int t = 0; t < 1000; ++t) {
        const float as = (t < 111) ? amp * Wv[t] : 0.0f;

        // ---- phase A: in-place stencil with 2-row q-lag ----
        if (act) {
            float4 hu2 = LD4(Ps, pc0 - 2 * SROW);
            float4 hu1 = LD4(Ps, pc0 - 1 * SROW);
            float4 hd1 = make_float4(0.f, 0.f, 0.f, 0.f);
            float4 hd2 = make_float4(0.f, 0.f, 0.f, 0.f);
            float4 qm2 = make_float4(0.f, 0.f, 0.f, 0.f);
            float4 qm1 = make_float4(0.f, 0.f, 0.f, 0.f);
            #pragma unroll
            for (int r = 0; r < RH; ++r) {
                if (r < zlim) {
                    if (r == 8) {                       // z-halo below, 1-row lead
                        hd1 = LD4(Ps, pc0 + RH * SROW);
                        hd2 = LD4(Ps, pc0 + (RH + 1) * SROW);
                    }
                    const int pc = pc0 + r * SROW;
                    float2 hl = LD2(Ps, pc - 2);        // cells x0-2, x0-1
                    float2 hr = LD2(Ps, pc + 4);        // cells x0+4, x0+5
                    float4 al4 = AL4[cb0 + r * 40];
                    float4 t14 = T14[cb0 + r * 40];
                    float4 t24 = T24[cb0 + r * 40];     // negated temp2
                    float4 c  = pA[r];
                    float4 u1 = (r == 0) ? hu1 : pA[(r >= 1) ? r - 1 : 0];
                    float4 u2 = (r == 0) ? hu2 :
                                ((r == 1) ? hu1 : pA[(r >= 2) ? r - 2 : 0]);
                    float4 d1 = (r == RH - 1) ? hd1 : pA[(r + 1 < RH) ? r + 1 : 0];
                    float4 d2 = (r == RH - 1) ? hd2 :
                                ((r == RH - 2) ? hd1 : pA[(r + 2 < RH) ? r + 2 : 0]);
                    float4 p0 = p0r[r];
                    float4 q;
                    q.x = cellq(hl.x, hl.y, c.x, c.y, c.z,
                                u1.x, u2.x, d1.x, d2.x, al4.x, t14.x, t24.x, p0.x);
                    q.y = cellq(hl.y, c.x, c.y, c.z, c.w,
                                u1.y, u2.y, d1.y, d2.y, al4.y, t14.y, t24.y, p0.y);
                    q.z = cellq(c.x, c.y, c.z, c.w, hr.x,
                                u1.z, u2.z, d1.z, d2.z, al4.z, t14.z, t24.z, p0.z);
                    q.w = cellq(c.y, c.z, c.w, hr.x, hr.y,
                                u1.w, u2.w, d1.w, d2.w, al4.w, t14.w, t24.w, p0.w);
                    if (r == 9 && isrc) {               // source injection (z=31)
                        q.x += (ls == 0) ? as : 0.0f;
                        q.y += (ls == 1) ? as : 0.0f;
                        q.z += (ls == 2) ? as : 0.0f;
                        q.w += (ls == 3) ? as : 0.0f;
                    }
                    if (r == 9 && grec) {               // receivers z=31, x=30..129
                        const int ob = shot * 100000 + t * 100 + xr0;
                        if (xr0 >= 0   && xr0 <= 99)  out[ob]     = q.x;
                        if (xr0 >= -1  && xr0 <= 98)  out[ob + 1] = q.y;
                        if (xr0 >= -2  && xr0 <= 97)  out[ob + 2] = q.z;
                        if (xr0 >= -3  && xr0 <= 96)  out[ob + 3] = q.w;
                    }
                    p0r[r] = c;                         // p0 <- old p1 center
                    // q-lag commit: rows r-1, r have consumed old pA[r-2]
                    if (r >= 2) pA[(r >= 2) ? r - 2 : 0] = qm2;
                    qm2 = qm1;
                    qm1 = q;
                }
            }
            // tail: commit the last two rows
            if (zlim == 11) { pA[9] = qm2; pA[10] = qm1; }
            else            { pA[7] = qm2; pA[8] = qm1; }   // g == 11 (zlim 9)
        }
        __syncthreads();               // all Ps reads complete

        // ---- phase B: commit p_new (now in pA) to Ps ----
        if (act) {
            #pragma unroll
            for (int r = 0; r < RH; ++r)
                if (r < zlim) ST4(Ps, pc0 + r * SROW, pA[r]);
        }
        __syncthreads();               // new p1 visible for next step
    }
}

extern "C" void kernel_launch(void* const* d_in, const int* in_sizes, int n_in,
                              void* d_out, int out_size, void* d_ws, size_t ws_size,
                              hipStream_t stream) {
    const float* v = (const float*)d_in[0];
    float* ws = (float*)d_ws;                           // [0..999] wavelet, [1000..1009] amps, [1010] velmin
    float* AL = (float*)((char*)d_ws + 4096);           // 21120 floats (132 rows)
    float* T1 = (float*)((char*)d_ws + 4096 + 84480);   // 21120 floats
    float* T2 = (float*)((char*)d_ws + 4096 + 168960);  // 21120 floats (negated)
    float* out = (float*)d_out;

    fwi_setup1<<<1, 1024, 0, stream>>>(v, ws);
    fwi_setup2<<<83, 256, 0, stream>>>(v, ws, AL, T1, T2);
    fwi_main<<<10, 512, 0, stream>>>((const float4*)AL, (const float4*)T1,
                                     (const float4*)T2, ws, out);
}

// Round 15
// 2530.502 us; speedup vs baseline: 1.0848x; 1.0848x over previous
//
#include <hip/hip_runtime.h>
#include <math.h>

// FWI forward: 10 shots, 1000 steps, padded grid 130x160 (NBC=30).
// R15: two-generation register swap (R7's copy-free structure) at R14's
// proven register budget. R14 audit: ~915 VALU instr/wave-step vs ~484
// arithmetic minimum; ~90 of the overhead are movs forced by the one-gen
// structure (p0r[r]=c copy + q-lag pA[r-2]=qm2 commit). Two-gen kills both:
// q = cellq(CUR, OLD) written straight into OLD[r] (old gen IS p_new's home),
// CUR untouched -> becomes next OLD. No q-lag, no tail, no p0 copies.
// Persistent regs identical (pA+pB = 88 = R14's pA+p0r).
// Also: 3 coef streams interleaved into CST[quad][3] float4 triplets -> one
// base address per thread. Rest byte-identical to R14 (scalar cellq, negated
// T2, reg receivers, zlim guard; g11's zero rows CUR[9],CUR[10] never
// written = perpetual zero halo).

#define SROW 168                 // Ps row stride; col = x + 4
#define PSZ (136 * SROW)         // stored rows -2..133
#define RH 11                    // rows per thread
#define DTf 0.0008f
#define C2f 1.3333333333333333f  // 4/3
#define C3f (-0.08333333333333333f) // -1/12

#define LD4(arr, i) (*reinterpret_cast<const float4*>(&(arr)[i]))
#define LD2(arr, i) (*reinterpret_cast<const float2*>(&(arr)[i]))
#define ST4(arr, i, v) (*reinterpret_cast<float4*>(&(arr)[i]) = (v))

// ---------- setup 1: velmin reduction, Ricker wavelet, source amplitudes ----------
__global__ __launch_bounds__(1024) void fwi_setup1(const float* __restrict__ v,
                                                   float* __restrict__ ws) {
    int tid = threadIdx.x;
    float m = 3.402823466e38f;
    for (int i = tid; i < 7000; i += 1024) m = fminf(m, v[i]);
    #pragma unroll
    for (int off = 32; off > 0; off >>= 1) m = fminf(m, __shfl_down(m, off, 64));
    __shared__ float red[16];
    if ((tid & 63) == 0) red[tid >> 6] = m;
    __syncthreads();
    if (tid == 0) {
        float mm = red[0];
        for (int i = 1; i < 16; ++i) mm = fminf(mm, red[i]);
        ws[1010] = mm * 1000.0f + 3000.0f;   // denormalized velmin
    }
    // Ricker wavelet: nw=111, nc=55, f*dt*pi = 0.06283185307179587
    if (tid < 1000) {
        float w = 0.0f;
        if (tid < 111) {
            float a = (float)(55 - tid) * 0.06283185307179587f;
            float b = a * a;
            w = (1.0f - 2.0f * b) * expf(-b);
        }
        ws[tid] = w;
    }
    // src_amp[l] = ((v[1][11l]*1000+3000)*DT)^2
    if (tid >= 1000 && tid < 1010) {
        int l = tid - 1000;
        float vd = v[100 + 11 * l] * 1000.0f + 3000.0f;
        float bdt = vd * DTf;
        ws[tid] = bdt * bdt;
    }
}

// ---------- setup 2: interleaved per-quad constants CST[quad] = {AL4, T14, T2n4} ----------
__global__ __launch_bounds__(256) void fwi_setup2(const float* __restrict__ v,
                                                  const float* __restrict__ ws,
                                                  float* __restrict__ CST) {
    int c = blockIdx.x * 256 + threadIdx.x;
    if (c >= 130 * 160) return;
    float velmin = ws[1010];
    int z = c / 160;
    int x = c - z * 160;
    int iz = min(max(z - 30, 0), 69);
    int ix = min(max(x - 30, 0), 99);
    float vd = v[iz * 100 + ix] * 1000.0f + 3000.0f;
    float tt = vd * DTf / 10.0f;       // v*DT/DX
    float al = tt * tt;                // alpha
    int qx = max(29 - x, x - 130);
    int qz = max(29 - z, z - 100);
    int q = (qx >= 0) ? qx : qz;
    float kdt = 0.0f;
    if (q >= 0) {
        float kap3 = 3.0f * velmin * 16.118095650958319f / 580.0f; // 3*velmin*ln(1e7)/(2*290)
        float r = (float)q * (10.0f / 290.0f);
        kdt = kap3 * (r * r) * DTf;
    }
    int quad = c >> 2, j = c & 3;
    CST[quad * 12 + j]     = al;                  // alpha
    CST[quad * 12 + 4 + j] = 2.0f - 5.0f * al - kdt;  // temp1
    CST[quad * 12 + 8 + j] = kdt - 1.0f;          // NEGATED temp2
}

static __device__ __forceinline__ float cellq(float l2, float l1, float cc, float r1, float r2,
                                              float u1, float u2, float d1, float d2,
                                              float al, float t1, float t2n, float p0) {
    float lap = C2f * ((l1 + r1) + (u1 + d1)) + C3f * ((l2 + r2) + (u2 + d2));
    return (t1 * cc + t2n * p0) + al * lap;
}

// One timestep. CUR = current field (p1); OLD = previous field (p0); the new
// field overwrites OLD in place (CUR is only read -> no hazard, no copies).
#define STEP(CUR, OLD, T) do {                                                  \
    const float as = ((T) < 111) ? amp * Wv[(T)] : 0.0f;                        \
    if (act) {                                                                  \
        float4 hu2 = LD4(Ps, pc0 - 2 * SROW);                                   \
        float4 hu1 = LD4(Ps, pc0 - 1 * SROW);                                   \
        float4 hd1 = make_float4(0.f, 0.f, 0.f, 0.f);                           \
        float4 hd2 = make_float4(0.f, 0.f, 0.f, 0.f);                           \
        _Pragma("unroll")                                                       \
        for (int r = 0; r < RH; ++r) {                                          \
            if (r < zlim) {                                                     \
                if (r == 8) {                       /* z-halo below, 1-row lead */ \
                    hd1 = LD4(Ps, pc0 + RH * SROW);                             \
                    hd2 = LD4(Ps, pc0 + (RH + 1) * SROW);                       \
                }                                                               \
                const int pc = pc0 + r * SROW;                                  \
                float2 hl = LD2(Ps, pc - 2);        /* cells x0-2, x0-1 */      \
                float2 hr = LD2(Ps, pc + 4);        /* cells x0+4, x0+5 */      \
                float4 al4 = cst[r * 120];                                      \
                float4 t14 = cst[r * 120 + 1];                                  \
                float4 t24 = cst[r * 120 + 2];      /* negated temp2 */         \
                float4 c  = (CUR)[r];                                           \
                float4 u1 = (r == 0) ? hu1 : (CUR)[(r >= 1) ? r - 1 : 0];       \
                float4 u2 = (r == 0) ? hu2 :                                    \
                            ((r == 1) ? hu1 : (CUR)[(r >= 2) ? r - 2 : 0]);     \
                float4 d1 = (r == RH - 1) ? hd1 : (CUR)[(r + 1 < RH) ? r + 1 : 0]; \
                float4 d2 = (r == RH - 1) ? hd2 :                               \
                            ((r == RH - 2) ? hd1 : (CUR)[(r + 2 < RH) ? r + 2 : 0]); \
                float4 p0 = (OLD)[r];                                           \
                float4 q;                                                       \
                q.x = cellq(hl.x, hl.y, c.x, c.y, c.z,                          \
                            u1.x, u2.x, d1.x, d2.x, al4.x, t14.x, t24.x, p0.x); \
                q.y = cellq(hl.y, c.x, c.y, c.z, c.w,                           \
                            u1.y, u2.y, d1.y, d2.y, al4.y, t14.y, t24.y, p0.y); \
                q.z = cellq(c.x, c.y, c.z, c.w, hr.x,                           \
                            u1.z, u2.z, d1.z, d2.z, al4.z, t14.z, t24.z, p0.z); \
                q.w = cellq(c.y, c.z, c.w, hr.x, hr.y,                          \
                            u1.w, u2.w, d1.w, d2.w, al4.w, t14.w, t24.w, p0.w); \
                if (r == 9 && isrc) {               /* source injection (z=31) */ \
                    q.x += (ls == 0) ? as : 0.0f;                               \
                    q.y += (ls == 1) ? as : 0.0f;                               \
                    q.z += (ls == 2) ? as : 0.0f;                               \
                    q.w += (ls == 3) ? as : 0.0f;                               \
                }                                                               \
                if (r == 9 && grec) {               /* receivers z=31 */        \
                    const int ob = shot * 100000 + (T) * 100 + xr0;             \
                    if (xr0 >= 0  && xr0 <= 99) out[ob]     = q.x;              \
                    if (xr0 >= -1 && xr0 <= 98) out[ob + 1] = q.y;              \
                    if (xr0 >= -2 && xr0 <= 97) out[ob + 2] = q.z;              \
                    if (xr0 >= -3 && xr0 <= 96) out[ob + 3] = q.w;              \
                }                                                               \
                (OLD)[r] = q;                       /* in-place: old gen -> new */ \
            }                                                                   \
        }                                                                       \
    }                                                                           \
    __syncthreads();                    /* all Ps reads complete */             \
    if (act) {                                                                  \
        _Pragma("unroll")                                                       \
        for (int r = 0; r < RH; ++r)                                            \
            if (r < zlim) ST4(Ps, pc0 + r * SROW, (OLD)[r]);                    \
    }                                                                           \
    __syncthreads();                    /* new p1 visible for next step */      \
} while (0)

// ---------- main: one block per shot, 1000 steps ----------
__global__ __launch_bounds__(512) void fwi_main(const float4* __restrict__ CST4,
                                                const float* __restrict__ ws,
                                                float* __restrict__ out) {
    __shared__ float Ps[PSZ];      // p1 mirror, haloed (91,392 B)
    __shared__ float Wv[128];      // Ricker wavelet (nonzero only t < 111)
    const int tid = threadIdx.x;
    const int shot = blockIdx.x;

    for (int i = tid; i < PSZ; i += 512) Ps[i] = 0.0f;
    if (tid < 128) Wv[tid] = (tid < 111) ? ws[tid] : 0.0f;

    const int g  = tid / 40;            // z-group 0..11 active, >=12 idle
    const int qx = tid - g * 40;        // x-quad 0..39, cells x0 = 4*qx
    const int z0 = g * RH;
    const bool act = (g < 12);
    const float amp = ws[1000 + shot];
    const int xs = 30 + 11 * shot;      // source x (z=31 -> g=2, r=9)
    const bool isrc = act && (g == 2) && (qx == (xs >> 2));
    const int ls = xs & 3;
    const int pc0 = (z0 + 2) * SROW + 4 * qx + 4;  // Ps index of row z0 quad
    const float4* cst = CST4 + (size_t)(z0 * 40 + qx) * 3;  // interleaved coefs
    const int zlim = min(130 - z0, RH);            // g<11: 11, g==11: 9
    const bool grec = act && (g == 2);             // this thread's r==9 is z=31
    const int xr0 = 4 * qx - 30;                   // receiver index of lane j=0

    float4 pA[RH], pB[RH];              // two field generations, all in regs
    #pragma unroll
    for (int r = 0; r < RH; ++r) {
        pA[r] = make_float4(0.f, 0.f, 0.f, 0.f);
        pB[r] = make_float4(0.f, 0.f, 0.f, 0.f);
    }
    __syncthreads();

    for (int t = 0; t < 1000; t += 2) {
        STEP(pB, pA, t);       // p1=pB, p0=pA -> new field lands in pA
        STEP(pA, pB, t + 1);   // roles swapped; static register names
    }
}

extern "C" void kernel_launch(void* const* d_in, const int* in_sizes, int n_in,
                              void* d_out, int out_size, void* d_ws, size_t ws_size,
                              hipStream_t stream) {
    const float* v = (const float*)d_in[0];
    float* ws = (float*)d_ws;                     // [0..999] wavelet, [1000..1009] amps, [1010] velmin
    float* CST = (float*)((char*)d_ws + 4096);    // 5200 quads x 12 floats (249,600 B)
    float* out = (float*)d_out;

    fwi_setup1<<<1, 1024, 0, stream>>>(v, ws);
    fwi_setup2<<<82, 256, 0, stream>>>(v, ws, CST);
    fwi_main<<<10, 512, 0, stream>>>((const float4*)CST, ws, out);
}

// Round 16
// 1988.300 us; speedup vs baseline: 1.3806x; 1.2727x over previous
//
#include <hip/hip_runtime.h>
#include <math.h>

// FWI forward: 10 shots, 1000 steps, padded grid 130x160 (NBC=30).
// R16: temporal blocking. 8 z-segments/shot (80 blocks, 8x CUs). Each block
// stores interior (16|18 rows) + 16 halo rows/side and runs K=8 sub-steps
// locally (zero-BC at cuts -> garbage spreads 2 rows/sub-step inward,
// exactly consumed by the halo; interior stays bit-exact). Every epoch
// (8 steps) blocks exchange interior p1+p0 via agent-scope u64 atomics
// (R10-proven), epoch-parity double-buffered G + monotonic flags, then
// reload halo registers. Sub-step = R15's two-gen register STEP with RH=4.
// Source injected by any block storing global row 31 (uniform predicate);
// receivers from seg-1 (row 31 interior, never garbage).

#define SROW 168                 // Ps row stride; col = x + 4
#define PS_ROWS 52               // slots -2..49
#define PSZ (PS_ROWS * SROW)
#define P0ROW 164                // Ps0 row stride (4 mod 32, 16B-aligned)
#define P0Z (48 * P0ROW)
#define RH 4
#define DTf 0.0008f
#define C2f 1.3333333333333333f
#define C3f (-0.08333333333333333f)

#define CST_OFF 4096
#define G_OFF   262144           // bytes; 4 bufs x 10 shots x 10400 u64
#define FLAG_OFF 3590144         // bytes; 80 u32
#define GSEG 10400               // u64 per (buf, shot) = 130 rows x 80

#define LD4(arr, i) (*reinterpret_cast<const float4*>(&(arr)[i]))
#define LD2(arr, i) (*reinterpret_cast<const float2*>(&(arr)[i]))
#define ST4(arr, i, v) (*reinterpret_cast<float4*>(&(arr)[i]) = (v))

// ---------- setup 1: velmin, wavelet, amps, zero flags ----------
__global__ __launch_bounds__(1024) void fwi_setup1(const float* __restrict__ v,
                                                   float* __restrict__ ws,
                                                   unsigned int* __restrict__ flags) {
    int tid = threadIdx.x;
    if (tid < 80) flags[tid] = 0u;
    float m = 3.402823466e38f;
    for (int i = tid; i < 7000; i += 1024) m = fminf(m, v[i]);
    #pragma unroll
    for (int off = 32; off > 0; off >>= 1) m = fminf(m, __shfl_down(m, off, 64));
    __shared__ float red[16];
    if ((tid & 63) == 0) red[tid >> 6] = m;
    __syncthreads();
    if (tid == 0) {
        float mm = red[0];
        for (int i = 1; i < 16; ++i) mm = fminf(mm, red[i]);
        ws[1010] = mm * 1000.0f + 3000.0f;
    }
    if (tid < 1000) {
        float w = 0.0f;
        if (tid < 111) {
            float a = (float)(55 - tid) * 0.06283185307179587f;
            float b = a * a;
            w = (1.0f - 2.0f * b) * expf(-b);
        }
        ws[tid] = w;
    }
    if (tid >= 1000 && tid < 1010) {
        int l = tid - 1000;
        float vd = v[100 + 11 * l] * 1000.0f + 3000.0f;
        float bdt = vd * DTf;
        ws[tid] = bdt * bdt;
    }
}

// ---------- setup 2: interleaved per-quad constants CST[quad] = {AL4,T14,T2n4} ----------
__global__ __launch_bounds__(256) void fwi_setup2(const float* __restrict__ v,
                                                  const float* __restrict__ ws,
                                                  float* __restrict__ CST) {
    int c = blockIdx.x * 256 + threadIdx.x;
    if (c >= 130 * 160) return;
    float velmin = ws[1010];
    int z = c / 160;
    int x = c - z * 160;
    int iz = min(max(z - 30, 0), 69);
    int ix = min(max(x - 30, 0), 99);
    float vd = v[iz * 100 + ix] * 1000.0f + 3000.0f;
    float tt = vd * DTf / 10.0f;
    float al = tt * tt;
    int qx = max(29 - x, x - 130);
    int qz = max(29 - z, z - 100);
    int q = (qx >= 0) ? qx : qz;
    float kdt = 0.0f;
    if (q >= 0) {
        float kap3 = 3.0f * velmin * 16.118095650958319f / 580.0f;
        float r = (float)q * (10.0f / 290.0f);
        kdt = kap3 * (r * r) * DTf;
    }
    int quad = c >> 2, j = c & 3;
    CST[quad * 12 + j]     = al;
    CST[quad * 12 + 4 + j] = 2.0f - 5.0f * al - kdt;  // temp1
    CST[quad * 12 + 8 + j] = kdt - 1.0f;              // negated temp2
}

static __device__ __forceinline__ float cellq(float l2, float l1, float cc, float r1, float r2,
                                              float u1, float u2, float d1, float d2,
                                              float al, float t1, float t2n, float p0) {
    float lap = C2f * ((l1 + r1) + (u1 + d1)) + C3f * ((l2 + r2) + (u2 + d2));
    return (t1 * cc + t2n * p0) + al * lap;
}

static __device__ __forceinline__ float4 ld_remote16(const unsigned long long* p) {
    union { unsigned long long u; float2 f; } a, b;
    a.u = __hip_atomic_load(p,     __ATOMIC_RELAXED, __HIP_MEMORY_SCOPE_AGENT);
    b.u = __hip_atomic_load(p + 1, __ATOMIC_RELAXED, __HIP_MEMORY_SCOPE_AGENT);
    return make_float4(a.f.x, a.f.y, b.f.x, b.f.y);
}
static __device__ __forceinline__ void st_remote16(unsigned long long* p, float4 v) {
    union { unsigned long long u; float2 f; } c;
    c.f = make_float2(v.x, v.y);
    __hip_atomic_store(p,     c.u, __ATOMIC_RELAXED, __HIP_MEMORY_SCOPE_AGENT);
    c.f = make_float2(v.z, v.w);
    __hip_atomic_store(p + 1, c.u, __ATOMIC_RELAXED, __HIP_MEMORY_SCOPE_AGENT);
}

// One sub-step: CUR = p1 regs (read-only), OLD = p0 regs (overwritten with new).
// LASTF: also mirror CUR (which becomes p0) into Ps0 for the epoch exchange.
#define STEP(CUR, OLD, T, LASTF) do {                                           \
    const int Ti = (T);                                                         \
    const float as = (Ti < 111) ? amp * Wv[Ti] : 0.0f;                          \
    if (act) {                                                                  \
        float4 hu2 = LD4(Ps, pc0 - 2 * SROW);                                   \
        float4 hu1 = LD4(Ps, pc0 - 1 * SROW);                                   \
        float4 hd1 = make_float4(0.f,0.f,0.f,0.f);                              \
        float4 hd2 = make_float4(0.f,0.f,0.f,0.f);                              \
        _Pragma("unroll")                                                       \
        for (int r = 0; r < RH; ++r) {                                          \
            if (r < zlim) {                                                     \
                if (r == 1) {                                                   \
                    hd1 = LD4(Ps, pc0 + RH * SROW);                             \
                    hd2 = LD4(Ps, pc0 + (RH + 1) * SROW);                       \
                }                                                               \
                const int pc = pc0 + r * SROW;                                  \
                float2 hl = LD2(Ps, pc - 2);                                    \
                float2 hr = LD2(Ps, pc + 4);                                    \
                float4 al4 = cst[r * 120];                                      \
                float4 t14 = cst[r * 120 + 1];                                  \
                float4 t24 = cst[r * 120 + 2];                                  \
                float4 c  = (CUR)[r];                                           \
                float4 u1 = (r == 0) ? hu1 : (CUR)[(r >= 1) ? r - 1 : 0];       \
                float4 u2 = (r == 0) ? hu2 :                                    \
                            ((r == 1) ? hu1 : (CUR)[(r >= 2) ? r - 2 : 0]);     \
                float4 d1 = (r == RH-1) ? hd1 : (CUR)[(r+1 < RH) ? r+1 : 0];    \
                float4 d2 = (r == RH-1) ? hd2 :                                 \
                            ((r == RH-2) ? hd1 : (CUR)[(r+2 < RH) ? r+2 : 0]);  \
                float4 p0 = (OLD)[r];                                           \
                float4 q;                                                       \
                q.x = cellq(hl.x, hl.y, c.x, c.y, c.z,                          \
                            u1.x, u2.x, d1.x, d2.x, al4.x, t14.x, t24.x, p0.x); \
                q.y = cellq(hl.y, c.x, c.y, c.z, c.w,                           \
                            u1.y, u2.y, d1.y, d2.y, al4.y, t14.y, t24.y, p0.y); \
                q.z = cellq(c.x, c.y, c.z, c.w, hr.x,                           \
                            u1.z, u2.z, d1.z, d2.z, al4.z, t14.z, t24.z, p0.z); \
                q.w = cellq(c.y, c.z, c.w, hr.x, hr.y,                          \
                            u1.w, u2.w, d1.w, d2.w, al4.w, t14.w, t24.w, p0.w); \
                if ((gr * 4 + r) == s31 && isq) {   /* source, global z==31 */  \
                    q.x += (ls == 0) ? as : 0.0f;                               \
                    q.y += (ls == 1) ? as : 0.0f;                               \
                    q.z += (ls == 2) ? as : 0.0f;                               \
                    q.w += (ls == 3) ? as : 0.0f;                               \
                }                                                               \
                (OLD)[r] = q;                                                   \
            }                                                                   \
        }                                                                       \
    }                                                                           \
    __syncthreads();                        /* all Ps reads complete */         \
    if (act) {                                                                  \
        _Pragma("unroll")                                                       \
        for (int r = 0; r < RH; ++r)                                            \
            if (r < zlim) {                                                     \
                ST4(Ps, pc0 + r * SROW, (OLD)[r]);                              \
                if (LASTF) ST4(Ps0, p0c + r * P0ROW, (CUR)[r]);                 \
            }                                                                   \
    }                                                                           \
    __syncthreads();                        /* new p1 visible */                \
    if (rec && tid < 100)                   /* receivers: z=31 (seg1 interior) */\
        out[shot * 100000 + Ti * 100 + tid] = Ps[33 * SROW + 34 + tid];         \
} while (0)

#define EXCHANGE(E) do {                                                        \
    const int par = (E) & 1;                                                    \
    for (int idx = tid; idx < int_n * 40; idx += 512) {    /* export interior */\
        int rr = idx / 40, q = idx - rr * 40;                                   \
        int slot = halo_top + rr, grow = int_base + rr;                         \
        float4 v1 = LD4(Ps, (slot + 2) * SROW + 4 * q + 4);                     \
        float4 v0 = LD4(Ps0, slot * P0ROW + 4 * q);                             \
        size_t b1 = ((size_t)(par*2+0)*10 + shot)*GSEG + (size_t)grow*80 + 2*q; \
        size_t b0 = ((size_t)(par*2+1)*10 + shot)*GSEG + (size_t)grow*80 + 2*q; \
        st_remote16(Gu + b1, v1);                                               \
        st_remote16(Gu + b0, v0);                                               \
    }                                                                           \
    __syncthreads();                        /* exports drained (vmcnt) */       \
    if (tid == 0)                                                               \
        __hip_atomic_store(&flags[(shot << 3) + seg], (unsigned)(E) + 1u,       \
                           __ATOMIC_RELEASE, __HIP_MEMORY_SCOPE_AGENT);         \
    if (tid == 16 && seg > 0)                                                   \
        while (__hip_atomic_load(&flags[(shot << 3) + seg - 1], __ATOMIC_ACQUIRE,\
                                 __HIP_MEMORY_SCOPE_AGENT) <= (unsigned)(E)) {} \
    if (tid == 32 && seg < 7)                                                   \
        while (__hip_atomic_load(&flags[(shot << 3) + seg + 1], __ATOMIC_ACQUIRE,\
                                 __HIP_MEMORY_SCOPE_AGENT) <= (unsigned)(E)) {} \
    __syncthreads();                                                            \
    for (int idx = tid; idx < (nh_top + nh_bot) * 40; idx += 512) { /* import */\
        int rr = idx / 40, q = idx - rr * 40;                                   \
        int slot = (rr < nh_top) ? rr : (halo_top + int_n + (rr - nh_top));     \
        int grow = base + slot;                                                 \
        size_t b1 = ((size_t)(par*2+0)*10 + shot)*GSEG + (size_t)grow*80 + 2*q; \
        size_t b0 = ((size_t)(par*2+1)*10 + shot)*GSEG + (size_t)grow*80 + 2*q; \
        float4 v1 = ld_remote16(Gu + b1);                                       \
        float4 v0 = ld_remote16(Gu + b0);                                       \
        ST4(Ps, (slot + 2) * SROW + 4 * q + 4, v1);                             \
        ST4(Ps0, slot * P0ROW + 4 * q, v0);                                     \
    }                                                                           \
    __syncthreads();                                                            \
    if (act) {                              /* reload halo-slot registers */    \
        _Pragma("unroll")                                                       \
        for (int r = 0; r < RH; ++r) {                                          \
            int slot = gr * 4 + r;                                              \
            if (r < zlim && (slot < nh_top || slot >= halo_top + int_n)) {      \
                pB[r] = LD4(Ps, pc0 + r * SROW);                                \
                pA[r] = LD4(Ps0, p0c + r * P0ROW);                              \
            }                                                                   \
        }                                                                       \
    }                                                                           \
    __syncthreads();                                                            \
} while (0)

// ---------- main: 80 blocks = 10 shots x 8 z-segments ----------
__global__ __launch_bounds__(512) void fwi_main(const float4* __restrict__ CST4,
                                                const float* __restrict__ ws,
                                                unsigned long long* __restrict__ Gu,
                                                unsigned int* __restrict__ flags,
                                                float* __restrict__ out) {
    __shared__ float Ps[PSZ];      // p1 mirror, slots -2..49 (34,944 B)
    __shared__ float Ps0[P0Z];     // p0 mirror for exchange (31,488 B)
    __shared__ float Wv[1024];     // wavelet, padded so Wv[T] is in-bounds
    const int tid = threadIdx.x;
    const int bid = blockIdx.x;
    const int shot = bid >> 3, seg = bid & 7;

    for (int i = tid; i < PSZ; i += 512) Ps[i] = 0.0f;
    for (int i = tid; i < P0Z; i += 512) Ps0[i] = 0.0f;
    for (int i = tid; i < 1024; i += 512) Wv[i] = (i < 111) ? ws[i] : 0.0f;

    const int int_base = 16 * seg;                 // interior global start row
    const int int_n = (seg < 7) ? 16 : 18;         // interior rows
    const int base = (seg > 0) ? int_base - 16 : 0;// stored global start row
    const int halo_top = (seg > 0) ? 16 : 0;
    const int stored_n = halo_top + int_n + ((seg < 7) ? 16 : 0); // 32|48|34
    const int nh_top = (seg > 0) ? 16 : 0;
    const int nh_bot = (seg < 7) ? 16 : 0;

    const int gr = tid / 40;                       // z-group 0..11 (RH=4 rows)
    const int qx = tid - gr * 40;                  // x-quad 0..39
    const int zlim = min(max(stored_n - gr * 4, 0), RH);
    const bool act = (gr < 12) && (zlim > 0);
    const float amp = ws[1000 + shot];
    const int xs = 30 + 11 * shot;
    const bool isq = (qx == (xs >> 2));
    const int ls = xs & 3;
    const int s31 = 31 - base;                     // stored slot of source row
    const int pc0 = (gr * 4 + 2) * SROW + 4 * qx + 4;
    const int p0c = (gr * 4) * P0ROW + 4 * qx;
    const float4* cst = CST4 + (size_t)((base + gr * 4) * 40 + qx) * 3;
    const bool rec = (seg == 1);                   // z=31 is seg1 interior

    float4 pA[RH], pB[RH];                         // two generations in regs
    #pragma unroll
    for (int r = 0; r < RH; ++r) {
        pA[r] = make_float4(0.f, 0.f, 0.f, 0.f);
        pB[r] = make_float4(0.f, 0.f, 0.f, 0.f);
    }
    __syncthreads();

    for (int e = 0; e < 125; ++e) {                // 125 epochs x 8 sub-steps
        for (int kk = 0; kk < 4; ++kk) {
            STEP(pB, pA, e * 8 + 2 * kk, false);
            STEP(pA, pB, e * 8 + 2 * kk + 1, (kk == 3));
        }
        if (e < 124) EXCHANGE(e);
    }
}

extern "C" void kernel_launch(void* const* d_in, const int* in_sizes, int n_in,
                              void* d_out, int out_size, void* d_ws, size_t ws_size,
                              hipStream_t stream) {
    const float* v = (const float*)d_in[0];
    float* ws = (float*)d_ws;
    float* CST = (float*)((char*)d_ws + CST_OFF);
    unsigned long long* Gu = (unsigned long long*)((char*)d_ws + G_OFF);
    unsigned int* flags = (unsigned int*)((char*)d_ws + FLAG_OFF);
    float* out = (float*)d_out;

    fwi_setup1<<<1, 1024, 0, stream>>>(v, ws, flags);
    fwi_setup2<<<82, 256, 0, stream>>>(v, ws, CST);
    fwi_main<<<80, 512, 0, stream>>>((const float4*)CST, ws, Gu, flags, out);
}

// Round 17
// 1911.473 us; speedup vs baseline: 1.4361x; 1.0402x over previous
//
#include <hip/hip_runtime.h>
#include <math.h>

// FWI forward: 10 shots, 1000 steps, padded grid 130x160 (NBC=30).
// R17 = R16 temporal blocking (80 blocks, K=8, 16-row halos, bit-exact) with
// three structural cuts:
//  1. Ps double-buffer: step T reads buf[T&1], writes buf[~T&1] -> ONE
//     barrier per sub-step (RAW/WAR separated by the swap); phase B merged
//     into phase A. Barriers/epoch 20 -> 11.
//  2. Exchange register-direct: owners export own interior rows from
//     pB(p1)/pA(p0); halo owners import into their own regs + write p1 to
//     PsA (the next even-T read buffer). Ps0 mirror + LASTF deleted.
//  3. Receivers stored from q regs (seg1, gr7, r3 = global row 31, last
//     interior row -> valid all 8 sub-steps).
// Epoch-parity G double-buffer + monotonic flags unchanged (R16-proven).

#define SROW 168                 // Ps row stride; col = x + 4
#define PS_ROWS 52               // slots -2..49
#define PSZ (PS_ROWS * SROW)
#define RH 4
#define DTf 0.0008f
#define C2f 1.3333333333333333f
#define C3f (-0.08333333333333333f)

#define CST_OFF 4096
#define G_OFF   262144           // bytes; 4 bufs x 10 shots x 10400 u64
#define FLAG_OFF 3590144         // bytes; 80 u32
#define GSEG 10400               // u64 per (buf, shot) = 130 rows x 80

#define LD4(arr, i) (*reinterpret_cast<const float4*>(&(arr)[i]))
#define LD2(arr, i) (*reinterpret_cast<const float2*>(&(arr)[i]))
#define ST4(arr, i, v) (*reinterpret_cast<float4*>(&(arr)[i]) = (v))

// ---------- setup 1: velmin, wavelet, amps, zero flags ----------
__global__ __launch_bounds__(1024) void fwi_setup1(const float* __restrict__ v,
                                                   float* __restrict__ ws,
                                                   unsigned int* __restrict__ flags) {
    int tid = threadIdx.x;
    if (tid < 80) flags[tid] = 0u;
    float m = 3.402823466e38f;
    for (int i = tid; i < 7000; i += 1024) m = fminf(m, v[i]);
    #pragma unroll
    for (int off = 32; off > 0; off >>= 1) m = fminf(m, __shfl_down(m, off, 64));
    __shared__ float red[16];
    if ((tid & 63) == 0) red[tid >> 6] = m;
    __syncthreads();
    if (tid == 0) {
        float mm = red[0];
        for (int i = 1; i < 16; ++i) mm = fminf(mm, red[i]);
        ws[1010] = mm * 1000.0f + 3000.0f;
    }
    if (tid < 1000) {
        float w = 0.0f;
        if (tid < 111) {
            float a = (float)(55 - tid) * 0.06283185307179587f;
            float b = a * a;
            w = (1.0f - 2.0f * b) * expf(-b);
        }
        ws[tid] = w;
    }
    if (tid >= 1000 && tid < 1010) {
        int l = tid - 1000;
        float vd = v[100 + 11 * l] * 1000.0f + 3000.0f;
        float bdt = vd * DTf;
        ws[tid] = bdt * bdt;
    }
}

// ---------- setup 2: interleaved per-quad constants CST[quad] = {AL4,T14,T2n4} ----------
__global__ __launch_bounds__(256) void fwi_setup2(const float* __restrict__ v,
                                                  const float* __restrict__ ws,
                                                  float* __restrict__ CST) {
    int c = blockIdx.x * 256 + threadIdx.x;
    if (c >= 130 * 160) return;
    float velmin = ws[1010];
    int z = c / 160;
    int x = c - z * 160;
    int iz = min(max(z - 30, 0), 69);
    int ix = min(max(x - 30, 0), 99);
    float vd = v[iz * 100 + ix] * 1000.0f + 3000.0f;
    float tt = vd * DTf / 10.0f;
    float al = tt * tt;
    int qx = max(29 - x, x - 130);
    int qz = max(29 - z, z - 100);
    int q = (qx >= 0) ? qx : qz;
    float kdt = 0.0f;
    if (q >= 0) {
        float kap3 = 3.0f * velmin * 16.118095650958319f / 580.0f;
        float r = (float)q * (10.0f / 290.0f);
        kdt = kap3 * (r * r) * DTf;
    }
    int quad = c >> 2, j = c & 3;
    CST[quad * 12 + j]     = al;
    CST[quad * 12 + 4 + j] = 2.0f - 5.0f * al - kdt;  // temp1
    CST[quad * 12 + 8 + j] = kdt - 1.0f;              // negated temp2
}

static __device__ __forceinline__ float cellq(float l2, float l1, float cc, float r1, float r2,
                                              float u1, float u2, float d1, float d2,
                                              float al, float t1, float t2n, float p0) {
    float lap = C2f * ((l1 + r1) + (u1 + d1)) + C3f * ((l2 + r2) + (u2 + d2));
    return (t1 * cc + t2n * p0) + al * lap;
}

static __device__ __forceinline__ float4 ld_remote16(const unsigned long long* p) {
    union { unsigned long long u; float2 f; } a, b;
    a.u = __hip_atomic_load(p,     __ATOMIC_RELAXED, __HIP_MEMORY_SCOPE_AGENT);
    b.u = __hip_atomic_load(p + 1, __ATOMIC_RELAXED, __HIP_MEMORY_SCOPE_AGENT);
    return make_float4(a.f.x, a.f.y, b.f.x, b.f.y);
}
static __device__ __forceinline__ void st_remote16(unsigned long long* p, float4 v) {
    union { unsigned long long u; float2 f; } c;
    c.f = make_float2(v.x, v.y);
    __hip_atomic_store(p,     c.u, __ATOMIC_RELAXED, __HIP_MEMORY_SCOPE_AGENT);
    c.f = make_float2(v.z, v.w);
    __hip_atomic_store(p + 1, c.u, __ATOMIC_RELAXED, __HIP_MEMORY_SCOPE_AGENT);
}

// One sub-step. CUR = p1 regs (read-only), OLD = p0 regs (overwritten with
// new p1). Reads halos from PR buffer, writes new p1 rows to PW buffer.
// ONE barrier (buffer swap removes the read-complete barrier).
#define STEP(CUR, OLD, T, PR, PW) do {                                          \
    const int Ti = (T);                                                         \
    const float as = (Ti < 111) ? amp * Wv[Ti] : 0.0f;                          \
    if (act) {                                                                  \
        float4 hu2 = LD4(PR, pc0 - 2 * SROW);                                   \
        float4 hu1 = LD4(PR, pc0 - 1 * SROW);                                   \
        float4 hd1 = make_float4(0.f,0.f,0.f,0.f);                              \
        float4 hd2 = make_float4(0.f,0.f,0.f,0.f);                              \
        _Pragma("unroll")                                                       \
        for (int r = 0; r < RH; ++r) {                                          \
            if (r < zlim) {                                                     \
                if (r == 1) {                                                   \
                    hd1 = LD4(PR, pc0 + RH * SROW);                             \
                    hd2 = LD4(PR, pc0 + (RH + 1) * SROW);                       \
                }                                                               \
                const int pc = pc0 + r * SROW;                                  \
                float2 hl = LD2(PR, pc - 2);                                    \
                float2 hr = LD2(PR, pc + 4);                                    \
                float4 al4 = cst[r * 120];                                      \
                float4 t14 = cst[r * 120 + 1];                                  \
                float4 t24 = cst[r * 120 + 2];                                  \
                float4 c  = (CUR)[r];                                           \
                float4 u1 = (r == 0) ? hu1 : (CUR)[(r >= 1) ? r - 1 : 0];       \
                float4 u2 = (r == 0) ? hu2 :                                    \
                            ((r == 1) ? hu1 : (CUR)[(r >= 2) ? r - 2 : 0]);     \
                float4 d1 = (r == RH-1) ? hd1 : (CUR)[(r+1 < RH) ? r+1 : 0];    \
                float4 d2 = (r == RH-1) ? hd2 :                                 \
                            ((r == RH-2) ? hd1 : (CUR)[(r+2 < RH) ? r+2 : 0]);  \
                float4 p0 = (OLD)[r];                                           \
                float4 q;                                                       \
                q.x = cellq(hl.x, hl.y, c.x, c.y, c.z,                          \
                            u1.x, u2.x, d1.x, d2.x, al4.x, t14.x, t24.x, p0.x); \
                q.y = cellq(hl.y, c.x, c.y, c.z, c.w,                           \
                            u1.y, u2.y, d1.y, d2.y, al4.y, t14.y, t24.y, p0.y); \
                q.z = cellq(c.x, c.y, c.z, c.w, hr.x,                           \
                            u1.z, u2.z, d1.z, d2.z, al4.z, t14.z, t24.z, p0.z); \
                q.w = cellq(c.y, c.z, c.w, hr.x, hr.y,                          \
                            u1.w, u2.w, d1.w, d2.w, al4.w, t14.w, t24.w, p0.w); \
                if ((gr * 4 + r) == s31 && isq) {   /* source, global z==31 */  \
                    q.x += (ls == 0) ? as : 0.0f;                               \
                    q.y += (ls == 1) ? as : 0.0f;                               \
                    q.z += (ls == 2) ? as : 0.0f;                               \
                    q.w += (ls == 3) ? as : 0.0f;                               \
                }                                                               \
                if (r == 3 && grec) {               /* receivers: row 31 */     \
                    const int ob = shot * 100000 + Ti * 100 + xr0;              \
                    if (xr0 >= 0  && xr0 <= 99) out[ob]     = q.x;              \
                    if (xr0 >= -1 && xr0 <= 98) out[ob + 1] = q.y;              \
                    if (xr0 >= -2 && xr0 <= 97) out[ob + 2] = q.z;              \
                    if (xr0 >= -3 && xr0 <= 96) out[ob + 3] = q.w;              \
                }                                                               \
                (OLD)[r] = q;                                                   \
                ST4(PW, pc0 + r * SROW, q);                                     \
            }                                                                   \
        }                                                                       \
    }                                                                           \
    __syncthreads();                        /* PW complete, PR reads done */    \
} while (0)

// Epoch exchange. At entry p1 = pB regs, p0 = pA regs; PsA holds current p1
// (written by the last odd sub-step). Owners export interior rows from regs;
// halo owners import into regs + PsA (next even-T read buffer).
#define EXCHANGE(E) do {                                                        \
    const int par = (E) & 1;                                                    \
    if (act) {                                                                  \
        _Pragma("unroll")                                                       \
        for (int r = 0; r < RH; ++r) {                                          \
            int slot = gr * 4 + r;                                              \
            if (r < zlim && slot >= halo_top && slot < halo_top + int_n) {      \
                int grow = base + slot;                                         \
                size_t b1 = ((size_t)(par*2+0)*10 + shot)*GSEG + (size_t)grow*80 + 2*qx; \
                size_t b0 = ((size_t)(par*2+1)*10 + shot)*GSEG + (size_t)grow*80 + 2*qx; \
                st_remote16(Gu + b1, pB[r]);                                    \
                st_remote16(Gu + b0, pA[r]);                                    \
            }                                                                   \
        }                                                                       \
    }                                                                           \
    __syncthreads();                        /* exports drained */               \
    if (tid == 0)                                                               \
        __hip_atomic_store(&flags[(shot << 3) + seg], (unsigned)(E) + 1u,       \
                           __ATOMIC_RELEASE, __HIP_MEMORY_SCOPE_AGENT);         \
    if (tid == 16 && seg > 0)                                                   \
        while (__hip_atomic_load(&flags[(shot << 3) + seg - 1], __ATOMIC_ACQUIRE,\
                                 __HIP_MEMORY_SCOPE_AGENT) <= (unsigned)(E)) {} \
    if (tid == 32 && seg < 7)                                                   \
        while (__hip_atomic_load(&flags[(shot << 3) + seg + 1], __ATOMIC_ACQUIRE,\
                                 __HIP_MEMORY_SCOPE_AGENT) <= (unsigned)(E)) {} \
    __syncthreads();                        /* neighbors' data ready */         \
    if (act) {                                                                  \
        _Pragma("unroll")                                                       \
        for (int r = 0; r < RH; ++r) {                                          \
            int slot = gr * 4 + r;                                              \
            if (r < zlim && (slot < halo_top || slot >= halo_top + int_n)) {    \
                int grow = base + slot;                                         \
                size_t b1 = ((size_t)(par*2+0)*10 + shot)*GSEG + (size_t)grow*80 + 2*qx; \
                size_t b0 = ((size_t)(par*2+1)*10 + shot)*GSEG + (size_t)grow*80 + 2*qx; \
                float4 v1 = ld_remote16(Gu + b1);                               \
                float4 v0 = ld_remote16(Gu + b0);                               \
                pB[r] = v1;                                                     \
                pA[r] = v0;                                                     \
                ST4(PsA, pc0 + r * SROW, v1);                                   \
            }                                                                   \
        }                                                                       \
    }                                                                           \
    __syncthreads();                        /* imported PsA rows visible */     \
} while (0)

// ---------- main: 80 blocks = 10 shots x 8 z-segments ----------
__global__ __launch_bounds__(512) void fwi_main(const float4* __restrict__ CST4,
                                                const float* __restrict__ ws,
                                                unsigned long long* __restrict__ Gu,
                                                unsigned int* __restrict__ flags,
                                                float* __restrict__ out) {
    __shared__ float PsA[PSZ];     // p1 mirror, even-T read buffer (34,944 B)
    __shared__ float PsB[PSZ];     // p1 mirror, odd-T read buffer (34,944 B)
    __shared__ float Wv[1024];     // wavelet, zero-padded
    const int tid = threadIdx.x;
    const int bid = blockIdx.x;
    const int shot = bid >> 3, seg = bid & 7;

    for (int i = tid; i < PSZ; i += 512) { PsA[i] = 0.0f; PsB[i] = 0.0f; }
    for (int i = tid; i < 1024; i += 512) Wv[i] = (i < 111) ? ws[i] : 0.0f;

    const int int_base = 16 * seg;                 // interior global start row
    const int int_n = (seg < 7) ? 16 : 18;         // interior rows
    const int base = (seg > 0) ? int_base - 16 : 0;// stored global start row
    const int halo_top = (seg > 0) ? 16 : 0;
    const int stored_n = halo_top + int_n + ((seg < 7) ? 16 : 0); // 32|48|34

    const int gr = tid / 40;                       // z-group 0..11 (RH=4 rows)
    const int qx = tid - gr * 40;                  // x-quad 0..39
    const int zlim = min(max(stored_n - gr * 4, 0), RH);
    const bool act = (gr < 12) && (zlim > 0);
    const float amp = ws[1000 + shot];
    const int xs = 30 + 11 * shot;
    const bool isq = (qx == (xs >> 2));
    const int ls = xs & 3;
    const int s31 = 31 - base;                     // stored slot of source row
    const int pc0 = (gr * 4 + 2) * SROW + 4 * qx + 4;
    const float4* cst = CST4 + (size_t)((base + gr * 4) * 40 + qx) * 3;
    const bool grec = (seg == 1) && (gr == 7);     // row 31 = seg1 slot 31 (gr7,r3)
    const int xr0 = 4 * qx - 30;                   // receiver index of lane j=0

    float4 pA[RH], pB[RH];                         // two generations in regs
    #pragma unroll
    for (int r = 0; r < RH; ++r) {
        pA[r] = make_float4(0.f, 0.f, 0.f, 0.f);
        pB[r] = make_float4(0.f, 0.f, 0.f, 0.f);
    }
    __syncthreads();

    for (int e = 0; e < 125; ++e) {                // 125 epochs x 8 sub-steps
        for (int kk = 0; kk < 4; ++kk) {
            STEP(pB, pA, e * 8 + 2 * kk,     PsA, PsB);  // even T: read A, write B
            STEP(pA, pB, e * 8 + 2 * kk + 1, PsB, PsA);  // odd T: read B, write A
        }
        if (e < 124) EXCHANGE(e);
    }
}

extern "C" void kernel_launch(void* const* d_in, const int* in_sizes, int n_in,
                              void* d_out, int out_size, void* d_ws, size_t ws_size,
                              hipStream_t stream) {
    const float* v = (const float*)d_in[0];
    float* ws = (float*)d_ws;
    float* CST = (float*)((char*)d_ws + CST_OFF);
    unsigned long long* Gu = (unsigned long long*)((char*)d_ws + G_OFF);
    unsigned int* flags = (unsigned int*)((char*)d_ws + FLAG_OFF);
    float* out = (float*)d_out;

    fwi_setup1<<<1, 1024, 0, stream>>>(v, ws, flags);
    fwi_setup2<<<82, 256, 0, stream>>>(v, ws, CST);
    fwi_main<<<80, 512, 0, stream>>>((const float4*)CST, ws, Gu, flags, out);
}

// Round 18
// 1753.788 us; speedup vs baseline: 1.5653x; 1.0899x over previous
//
#include <hip/hip_runtime.h>
#include <math.h>

// FWI forward: 10 shots, 1000 steps, padded grid 130x160 (NBC=30).
// R18 = R17 temporal blocking with 1024-thread blocks (RH=2) for 4 waves/SIMD.
// R17 analysis: sub-step 3,700cy vs ~1,150 LDS + ~1,000 VALU pipe-work ->
// ~65% latency stall at 2 waves/SIMD (1 block/CU). Doubling waves/SIMD lets
// TLP cover L2 coef-load + LDS latency. RH=2 -> per-thread state 16 regs
// (pA+pB), safe under even a 64-VGPR budget (R6 spill trap avoided).
// stored_n in {32,48,34} is even -> zlim in {0,2}: no partial groups.
// K=8 epochs, 16-row halos, PsA/PsB double-buffer, 1-barrier STEP,
// register-direct exchange + monotonic flags: unchanged (R16/R17-proven).

#define SROW 168                 // Ps row stride; col = x + 4
#define PS_ROWS 52               // slots -2..49
#define PSZ (PS_ROWS * SROW)
#define RH 2
#define DTf 0.0008f
#define C2f 1.3333333333333333f
#define C3f (-0.08333333333333333f)

#define CST_OFF 4096
#define G_OFF   262144           // bytes; 4 bufs x 10 shots x 10400 u64
#define FLAG_OFF 3590144         // bytes; 80 u32
#define GSEG 10400               // u64 per (buf, shot) = 130 rows x 80

#define LD4(arr, i) (*reinterpret_cast<const float4*>(&(arr)[i]))
#define LD2(arr, i) (*reinterpret_cast<const float2*>(&(arr)[i]))
#define ST4(arr, i, v) (*reinterpret_cast<float4*>(&(arr)[i]) = (v))

// ---------- setup 1: velmin, wavelet, amps, zero flags ----------
__global__ __launch_bounds__(1024) void fwi_setup1(const float* __restrict__ v,
                                                   float* __restrict__ ws,
                                                   unsigned int* __restrict__ flags) {
    int tid = threadIdx.x;
    if (tid < 80) flags[tid] = 0u;
    float m = 3.402823466e38f;
    for (int i = tid; i < 7000; i += 1024) m = fminf(m, v[i]);
    #pragma unroll
    for (int off = 32; off > 0; off >>= 1) m = fminf(m, __shfl_down(m, off, 64));
    __shared__ float red[16];
    if ((tid & 63) == 0) red[tid >> 6] = m;
    __syncthreads();
    if (tid == 0) {
        float mm = red[0];
        for (int i = 1; i < 16; ++i) mm = fminf(mm, red[i]);
        ws[1010] = mm * 1000.0f + 3000.0f;
    }
    if (tid < 1000) {
        float w = 0.0f;
        if (tid < 111) {
            float a = (float)(55 - tid) * 0.06283185307179587f;
            float b = a * a;
            w = (1.0f - 2.0f * b) * expf(-b);
        }
        ws[tid] = w;
    }
    if (tid >= 1000 && tid < 1010) {
        int l = tid - 1000;
        float vd = v[100 + 11 * l] * 1000.0f + 3000.0f;
        float bdt = vd * DTf;
        ws[tid] = bdt * bdt;
    }
}

// ---------- setup 2: interleaved per-quad constants CST[quad] = {AL4,T14,T2n4} ----------
__global__ __launch_bounds__(256) void fwi_setup2(const float* __restrict__ v,
                                                  const float* __restrict__ ws,
                                                  float* __restrict__ CST) {
    int c = blockIdx.x * 256 + threadIdx.x;
    if (c >= 130 * 160) return;
    float velmin = ws[1010];
    int z = c / 160;
    int x = c - z * 160;
    int iz = min(max(z - 30, 0), 69);
    int ix = min(max(x - 30, 0), 99);
    float vd = v[iz * 100 + ix] * 1000.0f + 3000.0f;
    float tt = vd * DTf / 10.0f;
    float al = tt * tt;
    int qx = max(29 - x, x - 130);
    int qz = max(29 - z, z - 100);
    int q = (qx >= 0) ? qx : qz;
    float kdt = 0.0f;
    if (q >= 0) {
        float kap3 = 3.0f * velmin * 16.118095650958319f / 580.0f;
        float r = (float)q * (10.0f / 290.0f);
        kdt = kap3 * (r * r) * DTf;
    }
    int quad = c >> 2, j = c & 3;
    CST[quad * 12 + j]     = al;
    CST[quad * 12 + 4 + j] = 2.0f - 5.0f * al - kdt;  // temp1
    CST[quad * 12 + 8 + j] = kdt - 1.0f;              // negated temp2
}

static __device__ __forceinline__ float cellq(float l2, float l1, float cc, float r1, float r2,
                                              float u1, float u2, float d1, float d2,
                                              float al, float t1, float t2n, float p0) {
    float lap = C2f * ((l1 + r1) + (u1 + d1)) + C3f * ((l2 + r2) + (u2 + d2));
    return (t1 * cc + t2n * p0) + al * lap;
}

static __device__ __forceinline__ float4 ld_remote16(const unsigned long long* p) {
    union { unsigned long long u; float2 f; } a, b;
    a.u = __hip_atomic_load(p,     __ATOMIC_RELAXED, __HIP_MEMORY_SCOPE_AGENT);
    b.u = __hip_atomic_load(p + 1, __ATOMIC_RELAXED, __HIP_MEMORY_SCOPE_AGENT);
    return make_float4(a.f.x, a.f.y, b.f.x, b.f.y);
}
static __device__ __forceinline__ void st_remote16(unsigned long long* p, float4 v) {
    union { unsigned long long u; float2 f; } c;
    c.f = make_float2(v.x, v.y);
    __hip_atomic_store(p,     c.u, __ATOMIC_RELAXED, __HIP_MEMORY_SCOPE_AGENT);
    c.f = make_float2(v.z, v.w);
    __hip_atomic_store(p + 1, c.u, __ATOMIC_RELAXED, __HIP_MEMORY_SCOPE_AGENT);
}

// One cell-row update (4 cells). Produces q from CUR/OLD regs + halos.
#define ROWQ4(q, c, p0, hl, hr, u1, u2, d1, d2, al4, t14, t24) do {             \
    (q).x = cellq((hl).x, (hl).y, (c).x, (c).y, (c).z,                          \
                  (u1).x, (u2).x, (d1).x, (d2).x, (al4).x, (t14).x, (t24).x, (p0).x); \
    (q).y = cellq((hl).y, (c).x, (c).y, (c).z, (c).w,                           \
                  (u1).y, (u2).y, (d1).y, (d2).y, (al4).y, (t14).y, (t24).y, (p0).y); \
    (q).z = cellq((c).x, (c).y, (c).z, (c).w, (hr).x,                           \
                  (u1).z, (u2).z, (d1).z, (d2).z, (al4).z, (t14).z, (t24).z, (p0).z); \
    (q).w = cellq((c).y, (c).z, (c).w, (hr).x, (hr).y,                          \
                  (u1).w, (u2).w, (d1).w, (d2).w, (al4).w, (t14).w, (t24).w, (p0).w); \
} while (0)

// One sub-step (RH=2). CUR = p1 regs (read-only), OLD = p0 regs (overwritten
// with new p1). Reads halos from PR, writes new p1 to PW. ONE barrier.
#define STEP(CUR, OLD, T, PR, PW) do {                                          \
    const int Ti = (T);                                                         \
    const float as = (Ti < 111) ? amp * Wv[Ti] : 0.0f;                          \
    if (act) {                                                                  \
        float4 hu2 = LD4(PR, pc0 - 2 * SROW);                                   \
        float4 hu1 = LD4(PR, pc0 - SROW);                                       \
        float4 hd1 = LD4(PR, pc0 + 2 * SROW);                                   \
        float4 hd2 = LD4(PR, pc0 + 3 * SROW);                                   \
        float2 hl0 = LD2(PR, pc0 - 2);                                          \
        float2 hr0 = LD2(PR, pc0 + 4);                                          \
        float2 hl1 = LD2(PR, pc0 + SROW - 2);                                   \
        float2 hr1 = LD2(PR, pc0 + SROW + 4);                                   \
        float4 a0 = cst[0], t0 = cst[1], s0 = cst[2];                           \
        float4 a1 = cst[120], t1c = cst[121], s1 = cst[122];                    \
        float4 q0, q1;                                                          \
        ROWQ4(q0, (CUR)[0], (OLD)[0], hl0, hr0, hu1, hu2, (CUR)[1], hd1, a0, t0, s0); \
        ROWQ4(q1, (CUR)[1], (OLD)[1], hl1, hr1, (CUR)[0], hu1, hd1, hd2, a1, t1c, s1); \
        if (src0) {                                /* source row at slot gr*2 */ \
            q0.x += (ls == 0) ? as : 0.0f;                                      \
            q0.y += (ls == 1) ? as : 0.0f;                                      \
            q0.z += (ls == 2) ? as : 0.0f;                                      \
            q0.w += (ls == 3) ? as : 0.0f;                                      \
        }                                                                       \
        if (src1) {                                /* source row at slot gr*2+1 */ \
            q1.x += (ls == 0) ? as : 0.0f;                                      \
            q1.y += (ls == 1) ? as : 0.0f;                                      \
            q1.z += (ls == 2) ? as : 0.0f;                                      \
            q1.w += (ls == 3) ? as : 0.0f;                                      \
        }                                                                       \
        if (grec) {                                /* receivers: global row 31 */ \
            const int ob = shot * 100000 + Ti * 100 + xr0;                      \
            if (xr0 >= 0  && xr0 <= 99) out[ob]     = q1.x;                     \
            if (xr0 >= -1 && xr0 <= 98) out[ob + 1] = q1.y;                     \
            if (xr0 >= -2 && xr0 <= 97) out[ob + 2] = q1.z;                     \
            if (xr0 >= -3 && xr0 <= 96) out[ob + 3] = q1.w;                     \
        }                                                                       \
        (OLD)[0] = q0; (OLD)[1] = q1;                                           \
        ST4(PW, pc0, q0);                                                       \
        ST4(PW, pc0 + SROW, q1);                                                \
    }                                                                           \
    __syncthreads();                        /* PW complete, PR reads done */    \
} while (0)

// Epoch exchange (RH=2). At entry p1 = pB regs (also in PsA), p0 = pA regs.
#define EXCHANGE(E) do {                                                        \
    const int par = (E) & 1;                                                    \
    if (act) {                                                                  \
        _Pragma("unroll")                                                       \
        for (int r = 0; r < RH; ++r) {                                          \
            int slot = gr * 2 + r;                                              \
            if (slot >= halo_top && slot < halo_top + int_n) {                  \
                int grow = base + slot;                                         \
                size_t b1 = ((size_t)(par*2+0)*10 + shot)*GSEG + (size_t)grow*80 + 2*qx; \
                size_t b0 = ((size_t)(par*2+1)*10 + shot)*GSEG + (size_t)grow*80 + 2*qx; \
                st_remote16(Gu + b1, pB[r]);                                    \
                st_remote16(Gu + b0, pA[r]);                                    \
            }                                                                   \
        }                                                                       \
    }                                                                           \
    __syncthreads();                        /* exports drained */               \
    if (tid == 0)                                                               \
        __hip_atomic_store(&flags[(shot << 3) + seg], (unsigned)(E) + 1u,       \
                           __ATOMIC_RELEASE, __HIP_MEMORY_SCOPE_AGENT);         \
    if (tid == 64 && seg > 0)                                                   \
        while (__hip_atomic_load(&flags[(shot << 3) + seg - 1], __ATOMIC_ACQUIRE,\
                                 __HIP_MEMORY_SCOPE_AGENT) <= (unsigned)(E)) {} \
    if (tid == 128 && seg < 7)                                                  \
        while (__hip_atomic_load(&flags[(shot << 3) + seg + 1], __ATOMIC_ACQUIRE,\
                                 __HIP_MEMORY_SCOPE_AGENT) <= (unsigned)(E)) {} \
    __syncthreads();                        /* neighbors' data ready */         \
    if (act) {                                                                  \
        _Pragma("unroll")                                                       \
        for (int r = 0; r < RH; ++r) {                                          \
            int slot = gr * 2 + r;                                              \
            if (slot < halo_top || slot >= halo_top + int_n) {                  \
                int grow = base + slot;                                         \
                size_t b1 = ((size_t)(par*2+0)*10 + shot)*GSEG + (size_t)grow*80 + 2*qx; \
                size_t b0 = ((size_t)(par*2+1)*10 + shot)*GSEG + (size_t)grow*80 + 2*qx; \
                float4 v1 = ld_remote16(Gu + b1);                               \
                float4 v0 = ld_remote16(Gu + b0);                               \
                pB[r] = v1;                                                     \
                pA[r] = v0;                                                     \
                ST4(PsA, pc0 + r * SROW, v1);                                   \
            }                                                                   \
        }                                                                       \
    }                                                                           \
    __syncthreads();                        /* imported PsA rows visible */     \
} while (0)

// ---------- main: 80 blocks = 10 shots x 8 z-segments, 1024 threads ----------
__global__ __launch_bounds__(1024, 4) void fwi_main(const float4* __restrict__ CST4,
                                                    const float* __restrict__ ws,
                                                    unsigned long long* __restrict__ Gu,
                                                    unsigned int* __restrict__ flags,
                                                    float* __restrict__ out) {
    __shared__ float PsA[PSZ];     // p1 mirror, even-T read buffer (34,944 B)
    __shared__ float PsB[PSZ];     // p1 mirror, odd-T read buffer (34,944 B)
    __shared__ float Wv[1024];     // wavelet, zero-padded
    const int tid = threadIdx.x;
    const int bid = blockIdx.x;
    const int shot = bid >> 3, seg = bid & 7;

    for (int i = tid; i < PSZ; i += 1024) { PsA[i] = 0.0f; PsB[i] = 0.0f; }
    Wv[tid] = (tid < 111) ? ws[tid] : 0.0f;

    const int int_base = 16 * seg;                 // interior global start row
    const int int_n = (seg < 7) ? 16 : 18;         // interior rows
    const int base = (seg > 0) ? int_base - 16 : 0;// stored global start row
    const int halo_top = (seg > 0) ? 16 : 0;
    const int stored_n = halo_top + int_n + ((seg < 7) ? 16 : 0); // 32|48|34 (even)

    const int gr = tid / 40;                       // z-group 0..24 (RH=2 rows)
    const int qx = tid - gr * 40;                  // x-quad 0..39
    const bool act = (gr < 24) && (gr * 2 < stored_n);
    const float amp = ws[1000 + shot];
    const int xs = 30 + 11 * shot;
    const bool isq = (qx == (xs >> 2));
    const int ls = xs & 3;
    const int s31 = 31 - base;                     // stored slot of source row
    const bool src0 = act && isq && (gr * 2 == s31);
    const bool src1 = act && isq && (gr * 2 + 1 == s31);
    const int pc0 = (gr * 2 + 2) * SROW + 4 * qx + 4;
    const float4* cst = CST4 + (size_t)((base + gr * 2) * 40 + qx) * 3;
    const bool grec = (seg == 1) && (gr == 15);    // slot 31 = global row 31 (r=1)
    const int xr0 = 4 * qx - 30;                   // receiver index of lane j=0

    float4 pA[RH], pB[RH];                         // two generations in regs
    #pragma unroll
    for (int r = 0; r < RH; ++r) {
        pA[r] = make_float4(0.f, 0.f, 0.f, 0.f);
        pB[r] = make_float4(0.f, 0.f, 0.f, 0.f);
    }
    __syncthreads();

    for (int e = 0; e < 125; ++e) {                // 125 epochs x 8 sub-steps
        for (int kk = 0; kk < 4; ++kk) {
            STEP(pB, pA, e * 8 + 2 * kk,     PsA, PsB);  // even T: read A, write B
            STEP(pA, pB, e * 8 + 2 * kk + 1, PsB, PsA);  // odd T: read B, write A
        }
        if (e < 124) EXCHANGE(e);
    }
}

extern "C" void kernel_launch(void* const* d_in, const int* in_sizes, int n_in,
                              void* d_out, int out_size, void* d_ws, size_t ws_size,
                              hipStream_t stream) {
    const float* v = (const float*)d_in[0];
    float* ws = (float*)d_ws;
    float* CST = (float*)((char*)d_ws + CST_OFF);
    unsigned long long* Gu = (unsigned long long*)((char*)d_ws + G_OFF);
    unsigned int* flags = (unsigned int*)((char*)d_ws + FLAG_OFF);
    float* out = (float*)d_out;

    fwi_setup1<<<1, 1024, 0, stream>>>(v, ws, flags);
    fwi_setup2<<<82, 256, 0, stream>>>(v, ws, CST);
    fwi_main<<<80, 1024, 0, stream>>>((const float4*)CST, ws, Gu, flags, out);
}

// Round 19
// 1433.414 us; speedup vs baseline: 1.9151x; 1.2235x over previous
//
#include <hip/hip_runtime.h>
#include <math.h>

// FWI forward: 10 shots, 1000 steps, padded grid 130x160 (NBC=30).
// R19 = R18 (80 blocks x 1024 thr, RH=2, K=8 temporal blocking, 1-barrier
// STEP, register-direct exchange) + ONE change: the 6 float4 coefficient
// loads (time-invariant!) are hoisted out of the sub-step loop into 24
// registers. R18 reloaded them from L2 every step: ~92KB/block-step of L2 BW
// + a 200-300cy latency chain inside every STEP. VGPR 52 -> ~80 (budget 128
// at waves_per_eu=4). Sub-step loop is now pure LDS+VALU.

#define SROW 168                 // Ps row stride; col = x + 4
#define PS_ROWS 52               // slots -2..49
#define PSZ (PS_ROWS * SROW)
#define RH 2
#define DTf 0.0008f
#define C2f 1.3333333333333333f
#define C3f (-0.08333333333333333f)

#define CST_OFF 4096
#define G_OFF   262144           // bytes; 4 bufs x 10 shots x 10400 u64
#define FLAG_OFF 3590144         // bytes; 80 u32
#define GSEG 10400               // u64 per (buf, shot) = 130 rows x 80

#define LD4(arr, i) (*reinterpret_cast<const float4*>(&(arr)[i]))
#define LD2(arr, i) (*reinterpret_cast<const float2*>(&(arr)[i]))
#define ST4(arr, i, v) (*reinterpret_cast<float4*>(&(arr)[i]) = (v))

// ---------- setup 1: velmin, wavelet, amps, zero flags ----------
__global__ __launch_bounds__(1024) void fwi_setup1(const float* __restrict__ v,
                                                   float* __restrict__ ws,
                                                   unsigned int* __restrict__ flags) {
    int tid = threadIdx.x;
    if (tid < 80) flags[tid] = 0u;
    float m = 3.402823466e38f;
    for (int i = tid; i < 7000; i += 1024) m = fminf(m, v[i]);
    #pragma unroll
    for (int off = 32; off > 0; off >>= 1) m = fminf(m, __shfl_down(m, off, 64));
    __shared__ float red[16];
    if ((tid & 63) == 0) red[tid >> 6] = m;
    __syncthreads();
    if (tid == 0) {
        float mm = red[0];
        for (int i = 1; i < 16; ++i) mm = fminf(mm, red[i]);
        ws[1010] = mm * 1000.0f + 3000.0f;
    }
    if (tid < 1000) {
        float w = 0.0f;
        if (tid < 111) {
            float a = (float)(55 - tid) * 0.06283185307179587f;
            float b = a * a;
            w = (1.0f - 2.0f * b) * expf(-b);
        }
        ws[tid] = w;
    }
    if (tid >= 1000 && tid < 1010) {
        int l = tid - 1000;
        float vd = v[100 + 11 * l] * 1000.0f + 3000.0f;
        float bdt = vd * DTf;
        ws[tid] = bdt * bdt;
    }
}

// ---------- setup 2: interleaved per-quad constants CST[quad] = {AL4,T14,T2n4} ----------
__global__ __launch_bounds__(256) void fwi_setup2(const float* __restrict__ v,
                                                  const float* __restrict__ ws,
                                                  float* __restrict__ CST) {
    int c = blockIdx.x * 256 + threadIdx.x;
    if (c >= 130 * 160) return;
    float velmin = ws[1010];
    int z = c / 160;
    int x = c - z * 160;
    int iz = min(max(z - 30, 0), 69);
    int ix = min(max(x - 30, 0), 99);
    float vd = v[iz * 100 + ix] * 1000.0f + 3000.0f;
    float tt = vd * DTf / 10.0f;
    float al = tt * tt;
    int qx = max(29 - x, x - 130);
    int qz = max(29 - z, z - 100);
    int q = (qx >= 0) ? qx : qz;
    float kdt = 0.0f;
    if (q >= 0) {
        float kap3 = 3.0f * velmin * 16.118095650958319f / 580.0f;
        float r = (float)q * (10.0f / 290.0f);
        kdt = kap3 * (r * r) * DTf;
    }
    int quad = c >> 2, j = c & 3;
    CST[quad * 12 + j]     = al;
    CST[quad * 12 + 4 + j] = 2.0f - 5.0f * al - kdt;  // temp1
    CST[quad * 12 + 8 + j] = kdt - 1.0f;              // negated temp2
}

static __device__ __forceinline__ float cellq(float l2, float l1, float cc, float r1, float r2,
                                              float u1, float u2, float d1, float d2,
                                              float al, float t1, float t2n, float p0) {
    float lap = C2f * ((l1 + r1) + (u1 + d1)) + C3f * ((l2 + r2) + (u2 + d2));
    return (t1 * cc + t2n * p0) + al * lap;
}

static __device__ __forceinline__ float4 ld_remote16(const unsigned long long* p) {
    union { unsigned long long u; float2 f; } a, b;
    a.u = __hip_atomic_load(p,     __ATOMIC_RELAXED, __HIP_MEMORY_SCOPE_AGENT);
    b.u = __hip_atomic_load(p + 1, __ATOMIC_RELAXED, __HIP_MEMORY_SCOPE_AGENT);
    return make_float4(a.f.x, a.f.y, b.f.x, b.f.y);
}
static __device__ __forceinline__ void st_remote16(unsigned long long* p, float4 v) {
    union { unsigned long long u; float2 f; } c;
    c.f = make_float2(v.x, v.y);
    __hip_atomic_store(p,     c.u, __ATOMIC_RELAXED, __HIP_MEMORY_SCOPE_AGENT);
    c.f = make_float2(v.z, v.w);
    __hip_atomic_store(p + 1, c.u, __ATOMIC_RELAXED, __HIP_MEMORY_SCOPE_AGENT);
}

// One cell-row update (4 cells). Produces q from CUR/OLD regs + halos.
#define ROWQ4(q, c, p0, hl, hr, u1, u2, d1, d2, al4, t14, t24) do {             \
    (q).x = cellq((hl).x, (hl).y, (c).x, (c).y, (c).z,                          \
                  (u1).x, (u2).x, (d1).x, (d2).x, (al4).x, (t14).x, (t24).x, (p0).x); \
    (q).y = cellq((hl).y, (c).x, (c).y, (c).z, (c).w,                           \
                  (u1).y, (u2).y, (d1).y, (d2).y, (al4).y, (t14).y, (t24).y, (p0).y); \
    (q).z = cellq((c).x, (c).y, (c).z, (c).w, (hr).x,                           \
                  (u1).z, (u2).z, (d1).z, (d2).z, (al4).z, (t14).z, (t24).z, (p0).z); \
    (q).w = cellq((c).y, (c).z, (c).w, (hr).x, (hr).y,                          \
                  (u1).w, (u2).w, (d1).w, (d2).w, (al4).w, (t14).w, (t24).w, (p0).w); \
} while (0)

// One sub-step (RH=2). CUR = p1 regs (read-only), OLD = p0 regs (overwritten
// with new p1). Coefs ca0..cs1 are register-resident (hoisted). ONE barrier.
#define STEP(CUR, OLD, T, PR, PW) do {                                          \
    const int Ti = (T);                                                         \
    const float as = (Ti < 111) ? amp * Wv[Ti] : 0.0f;                          \
    if (act) {                                                                  \
        float4 hu2 = LD4(PR, pc0 - 2 * SROW);                                   \
        float4 hu1 = LD4(PR, pc0 - SROW);                                       \
        float4 hd1 = LD4(PR, pc0 + 2 * SROW);                                   \
        float4 hd2 = LD4(PR, pc0 + 3 * SROW);                                   \
        float2 hl0 = LD2(PR, pc0 - 2);                                          \
        float2 hr0 = LD2(PR, pc0 + 4);                                          \
        float2 hl1 = LD2(PR, pc0 + SROW - 2);                                   \
        float2 hr1 = LD2(PR, pc0 + SROW + 4);                                   \
        float4 q0, q1;                                                          \
        ROWQ4(q0, (CUR)[0], (OLD)[0], hl0, hr0, hu1, hu2, (CUR)[1], hd1, ca0, ct0, cs0); \
        ROWQ4(q1, (CUR)[1], (OLD)[1], hl1, hr1, (CUR)[0], hu1, hd1, hd2, ca1, ct1, cs1); \
        if (src0) {                                /* source row at slot gr*2 */ \
            q0.x += (ls == 0) ? as : 0.0f;                                      \
            q0.y += (ls == 1) ? as : 0.0f;                                      \
            q0.z += (ls == 2) ? as : 0.0f;                                      \
            q0.w += (ls == 3) ? as : 0.0f;                                      \
        }                                                                       \
        if (src1) {                                /* source row at slot gr*2+1 */ \
            q1.x += (ls == 0) ? as : 0.0f;                                      \
            q1.y += (ls == 1) ? as : 0.0f;                                      \
            q1.z += (ls == 2) ? as : 0.0f;                                      \
            q1.w += (ls == 3) ? as : 0.0f;                                      \
        }                                                                       \
        if (grec) {                                /* receivers: global row 31 */ \
            const int ob = shot * 100000 + Ti * 100 + xr0;                      \
            if (xr0 >= 0  && xr0 <= 99) out[ob]     = q1.x;                     \
            if (xr0 >= -1 && xr0 <= 98) out[ob + 1] = q1.y;                     \
            if (xr0 >= -2 && xr0 <= 97) out[ob + 2] = q1.z;                     \
            if (xr0 >= -3 && xr0 <= 96) out[ob + 3] = q1.w;                     \
        }                                                                       \
        (OLD)[0] = q0; (OLD)[1] = q1;                                           \
        ST4(PW, pc0, q0);                                                       \
        ST4(PW, pc0 + SROW, q1);                                                \
    }                                                                           \
    __syncthreads();                        /* PW complete, PR reads done */    \
} while (0)

// Epoch exchange (RH=2). At entry p1 = pB regs (also in PsA), p0 = pA regs.
#define EXCHANGE(E) do {                                                        \
    const int par = (E) & 1;                                                    \
    if (act) {                                                                  \
        _Pragma("unroll")                                                       \
        for (int r = 0; r < RH; ++r) {                                          \
            int slot = gr * 2 + r;                                              \
            if (slot >= halo_top && slot < halo_top + int_n) {                  \
                int grow = base + slot;                                         \
                size_t b1 = ((size_t)(par*2+0)*10 + shot)*GSEG + (size_t)grow*80 + 2*qx; \
                size_t b0 = ((size_t)(par*2+1)*10 + shot)*GSEG + (size_t)grow*80 + 2*qx; \
                st_remote16(Gu + b1, pB[r]);                                    \
                st_remote16(Gu + b0, pA[r]);                                    \
            }                                                                   \
        }                                                                       \
    }                                                                           \
    __syncthreads();                        /* exports drained */               \
    if (tid == 0)                                                               \
        __hip_atomic_store(&flags[(shot << 3) + seg], (unsigned)(E) + 1u,       \
                           __ATOMIC_RELEASE, __HIP_MEMORY_SCOPE_AGENT);         \
    if (tid == 64 && seg > 0)                                                   \
        while (__hip_atomic_load(&flags[(shot << 3) + seg - 1], __ATOMIC_ACQUIRE,\
                                 __HIP_MEMORY_SCOPE_AGENT) <= (unsigned)(E)) {} \
    if (tid == 128 && seg < 7)                                                  \
        while (__hip_atomic_load(&flags[(shot << 3) + seg + 1], __ATOMIC_ACQUIRE,\
                                 __HIP_MEMORY_SCOPE_AGENT) <= (unsigned)(E)) {} \
    __syncthreads();                        /* neighbors' data ready */         \
    if (act) {                                                                  \
        _Pragma("unroll")                                                       \
        for (int r = 0; r < RH; ++r) {                                          \
            int slot = gr * 2 + r;                                              \
            if (slot < halo_top || slot >= halo_top + int_n) {                  \
                int grow = base + slot;                                         \
                size_t b1 = ((size_t)(par*2+0)*10 + shot)*GSEG + (size_t)grow*80 + 2*qx; \
                size_t b0 = ((size_t)(par*2+1)*10 + shot)*GSEG + (size_t)grow*80 + 2*qx; \
                float4 v1 = ld_remote16(Gu + b1);                               \
                float4 v0 = ld_remote16(Gu + b0);                               \
                pB[r] = v1;                                                     \
                pA[r] = v0;                                                     \
                ST4(PsA, pc0 + r * SROW, v1);                                   \
            }                                                                   \
        }                                                                       \
    }                                                                           \
    __syncthreads();                        /* imported PsA rows visible */     \
} while (0)

// ---------- main: 80 blocks = 10 shots x 8 z-segments, 1024 threads ----------
__global__ __launch_bounds__(1024, 4) void fwi_main(const float4* __restrict__ CST4,
                                                    const float* __restrict__ ws,
                                                    unsigned long long* __restrict__ Gu,
                                                    unsigned int* __restrict__ flags,
                                                    float* __restrict__ out) {
    __shared__ float PsA[PSZ];     // p1 mirror, even-T read buffer (34,944 B)
    __shared__ float PsB[PSZ];     // p1 mirror, odd-T read buffer (34,944 B)
    __shared__ float Wv[1024];     // wavelet, zero-padded
    const int tid = threadIdx.x;
    const int bid = blockIdx.x;
    const int shot = bid >> 3, seg = bid & 7;

    for (int i = tid; i < PSZ; i += 1024) { PsA[i] = 0.0f; PsB[i] = 0.0f; }
    Wv[tid] = (tid < 111) ? ws[tid] : 0.0f;

    const int int_base = 16 * seg;                 // interior global start row
    const int int_n = (seg < 7) ? 16 : 18;         // interior rows
    const int base = (seg > 0) ? int_base - 16 : 0;// stored global start row
    const int halo_top = (seg > 0) ? 16 : 0;
    const int stored_n = halo_top + int_n + ((seg < 7) ? 16 : 0); // 32|48|34 (even)

    const int gr = tid / 40;                       // z-group 0..24 (RH=2 rows)
    const int qx = tid - gr * 40;                  // x-quad 0..39
    const bool act = (gr < 24) && (gr * 2 < stored_n);
    const float amp = ws[1000 + shot];
    const int xs = 30 + 11 * shot;
    const bool isq = (qx == (xs >> 2));
    const int ls = xs & 3;
    const int s31 = 31 - base;                     // stored slot of source row
    const bool src0 = act && isq && (gr * 2 == s31);
    const bool src1 = act && isq && (gr * 2 + 1 == s31);
    const int pc0 = (gr * 2 + 2) * SROW + 4 * qx + 4;
    const float4* cst = CST4 + (size_t)((base + gr * 2) * 40 + qx) * 3;
    const bool grec = (seg == 1) && (gr == 15);    // slot 31 = global row 31 (r=1)
    const int xr0 = 4 * qx - 30;                   // receiver index of lane j=0

    // hoisted time-invariant coefficients (24 VGPRs) — the R19 change
    float4 ca0, ct0, cs0, ca1, ct1, cs1;
    ca0 = ct0 = cs0 = ca1 = ct1 = cs1 = make_float4(0.f, 0.f, 0.f, 0.f);
    if (act) {
        ca0 = cst[0];   ct0 = cst[1];   cs0 = cst[2];
        ca1 = cst[120]; ct1 = cst[121]; cs1 = cst[122];
    }

    float4 pA[RH], pB[RH];                         // two generations in regs
    #pragma unroll
    for (int r = 0; r < RH; ++r) {
        pA[r] = make_float4(0.f, 0.f, 0.f, 0.f);
        pB[r] = make_float4(0.f, 0.f, 0.f, 0.f);
    }
    __syncthreads();

    for (int e = 0; e < 125; ++e) {                // 125 epochs x 8 sub-steps
        for (int kk = 0; kk < 4; ++kk) {
            STEP(pB, pA, e * 8 + 2 * kk,     PsA, PsB);  // even T: read A, write B
            STEP(pA, pB, e * 8 + 2 * kk + 1, PsB, PsA);  // odd T: read B, write A
        }
        if (e < 124) EXCHANGE(e);
    }
}

extern "C" void kernel_launch(void* const* d_in, const int* in_sizes, int n_in,
                              void* d_out, int out_size, void* d_ws, size_t ws_size,
                              hipStream_t stream) {
    const float* v = (const float*)d_in[0];
    float* ws = (float*)d_ws;
    float* CST = (float*)((char*)d_ws + CST_OFF);
    unsigned long long* Gu = (unsigned long long*)((char*)d_ws + G_OFF);
    unsigned int* flags = (unsigned int*)((char*)d_ws + FLAG_OFF);
    float* out = (float*)d_out;

    fwi_setup1<<<1, 1024, 0, stream>>>(v, ws, flags);
    fwi_setup2<<<82, 256, 0, stream>>>(v, ws, CST);
    fwi_main<<<80, 1024, 0, stream>>>((const float4*)CST, ws, Gu, flags, out);
}

// Round 20
// 1276.677 us; speedup vs baseline: 2.1502x; 1.1228x over previous
//
#include <hip/hip_runtime.h>
#include <math.h>

// FWI forward: 10 shots, 1000 steps, padded grid 130x160 (NBC=30).
// R20 = R19 (80 blocks x 1024 thr, RH=2, K=8 temporal blocking, hoisted
// coefs, 1-barrier STEP, register-direct exchange) + trapezoid validity
// creep: at sub-step k only slots [2(k+1), stored-2(k+1)) (per cut side)
// are computed. Rows outside produce garbage nothing valid reads (same
// creep argument that makes the K=8/16-row-halo scheme bit-exact), so
// skipping them is free: middle segments 24 -> avg 15 active groups
// (-37% aggregate LDS+VALU; step is aggregate-LDS-bound).
// Interior [16,32) stays active through k=7 exactly -> exports, source,
// receivers untouched. Bounds always even -> group(2-row)-aligned.

#define SROW 168                 // Ps row stride; col = x + 4
#define PS_ROWS 52               // slots -2..49
#define PSZ (PS_ROWS * SROW)
#define RH 2
#define DTf 0.0008f
#define C2f 1.3333333333333333f
#define C3f (-0.08333333333333333f)

#define CST_OFF 4096
#define G_OFF   262144           // bytes; 4 bufs x 10 shots x 10400 u64
#define FLAG_OFF 3590144         // bytes; 80 u32
#define GSEG 10400               // u64 per (buf, shot) = 130 rows x 80

#define LD4(arr, i) (*reinterpret_cast<const float4*>(&(arr)[i]))
#define LD2(arr, i) (*reinterpret_cast<const float2*>(&(arr)[i]))
#define ST4(arr, i, v) (*reinterpret_cast<float4*>(&(arr)[i]) = (v))

// ---------- setup 1: velmin, wavelet, amps, zero flags ----------
__global__ __launch_bounds__(1024) void fwi_setup1(const float* __restrict__ v,
                                                   float* __restrict__ ws,
                                                   unsigned int* __restrict__ flags) {
    int tid = threadIdx.x;
    if (tid < 80) flags[tid] = 0u;
    float m = 3.402823466e38f;
    for (int i = tid; i < 7000; i += 1024) m = fminf(m, v[i]);
    #pragma unroll
    for (int off = 32; off > 0; off >>= 1) m = fminf(m, __shfl_down(m, off, 64));
    __shared__ float red[16];
    if ((tid & 63) == 0) red[tid >> 6] = m;
    __syncthreads();
    if (tid == 0) {
        float mm = red[0];
        for (int i = 1; i < 16; ++i) mm = fminf(mm, red[i]);
        ws[1010] = mm * 1000.0f + 3000.0f;
    }
    if (tid < 1000) {
        float w = 0.0f;
        if (tid < 111) {
            float a = (float)(55 - tid) * 0.06283185307179587f;
            float b = a * a;
            w = (1.0f - 2.0f * b) * expf(-b);
        }
        ws[tid] = w;
    }
    if (tid >= 1000 && tid < 1010) {
        int l = tid - 1000;
        float vd = v[100 + 11 * l] * 1000.0f + 3000.0f;
        float bdt = vd * DTf;
        ws[tid] = bdt * bdt;
    }
}

// ---------- setup 2: interleaved per-quad constants CST[quad] = {AL4,T14,T2n4} ----------
__global__ __launch_bounds__(256) void fwi_setup2(const float* __restrict__ v,
                                                  const float* __restrict__ ws,
                                                  float* __restrict__ CST) {
    int c = blockIdx.x * 256 + threadIdx.x;
    if (c >= 130 * 160) return;
    float velmin = ws[1010];
    int z = c / 160;
    int x = c - z * 160;
    int iz = min(max(z - 30, 0), 69);
    int ix = min(max(x - 30, 0), 99);
    float vd = v[iz * 100 + ix] * 1000.0f + 3000.0f;
    float tt = vd * DTf / 10.0f;
    float al = tt * tt;
    int qx = max(29 - x, x - 130);
    int qz = max(29 - z, z - 100);
    int q = (qx >= 0) ? qx : qz;
    float kdt = 0.0f;
    if (q >= 0) {
        float kap3 = 3.0f * velmin * 16.118095650958319f / 580.0f;
        float r = (float)q * (10.0f / 290.0f);
        kdt = kap3 * (r * r) * DTf;
    }
    int quad = c >> 2, j = c & 3;
    CST[quad * 12 + j]     = al;
    CST[quad * 12 + 4 + j] = 2.0f - 5.0f * al - kdt;  // temp1
    CST[quad * 12 + 8 + j] = kdt - 1.0f;              // negated temp2
}

static __device__ __forceinline__ float cellq(float l2, float l1, float cc, float r1, float r2,
                                              float u1, float u2, float d1, float d2,
                                              float al, float t1, float t2n, float p0) {
    float lap = C2f * ((l1 + r1) + (u1 + d1)) + C3f * ((l2 + r2) + (u2 + d2));
    return (t1 * cc + t2n * p0) + al * lap;
}

static __device__ __forceinline__ float4 ld_remote16(const unsigned long long* p) {
    union { unsigned long long u; float2 f; } a, b;
    a.u = __hip_atomic_load(p,     __ATOMIC_RELAXED, __HIP_MEMORY_SCOPE_AGENT);
    b.u = __hip_atomic_load(p + 1, __ATOMIC_RELAXED, __HIP_MEMORY_SCOPE_AGENT);
    return make_float4(a.f.x, a.f.y, b.f.x, b.f.y);
}
static __device__ __forceinline__ void st_remote16(unsigned long long* p, float4 v) {
    union { unsigned long long u; float2 f; } c;
    c.f = make_float2(v.x, v.y);
    __hip_atomic_store(p,     c.u, __ATOMIC_RELAXED, __HIP_MEMORY_SCOPE_AGENT);
    c.f = make_float2(v.z, v.w);
    __hip_atomic_store(p + 1, c.u, __ATOMIC_RELAXED, __HIP_MEMORY_SCOPE_AGENT);
}

// One cell-row update (4 cells). Produces q from CUR/OLD regs + halos.
#define ROWQ4(q, c, p0, hl, hr, u1, u2, d1, d2, al4, t14, t24) do {             \
    (q).x = cellq((hl).x, (hl).y, (c).x, (c).y, (c).z,                          \
                  (u1).x, (u2).x, (d1).x, (d2).x, (al4).x, (t14).x, (t24).x, (p0).x); \
    (q).y = cellq((hl).y, (c).x, (c).y, (c).z, (c).w,                           \
                  (u1).y, (u2).y, (d1).y, (d2).y, (al4).y, (t14).y, (t24).y, (p0).y); \
    (q).z = cellq((c).x, (c).y, (c).z, (c).w, (hr).x,                           \
                  (u1).z, (u2).z, (d1).z, (d2).z, (al4).z, (t14).z, (t24).z, (p0).z); \
    (q).w = cellq((c).y, (c).z, (c).w, (hr).x, (hr).y,                          \
                  (u1).w, (u2).w, (d1).w, (d2).w, (al4).w, (t14).w, (t24).w, (p0).w); \
} while (0)

// One sub-step (RH=2). CUR = p1 regs (read-only), OLD = p0 regs (overwritten
// with new p1). K = sub-step index within epoch (0..7) for validity creep.
#define STEP(CUR, OLD, T, K, PR, PW) do {                                       \
    const int Ti = (T);                                                         \
    const int kp1 = (K) + 1;                                                    \
    const bool actk = act && (gr >= (ct ? kp1 : 0)) && (gr < ng - (cb ? kp1 : 0)); \
    const float as = (Ti < 111) ? amp * Wv[Ti] : 0.0f;                          \
    if (actk) {                                                                 \
        float4 hu2 = LD4(PR, pc0 - 2 * SROW);                                   \
        float4 hu1 = LD4(PR, pc0 - SROW);                                       \
        float4 hd1 = LD4(PR, pc0 + 2 * SROW);                                   \
        float4 hd2 = LD4(PR, pc0 + 3 * SROW);                                   \
        float2 hl0 = LD2(PR, pc0 - 2);                                          \
        float2 hr0 = LD2(PR, pc0 + 4);                                          \
        float2 hl1 = LD2(PR, pc0 + SROW - 2);                                   \
        float2 hr1 = LD2(PR, pc0 + SROW + 4);                                   \
        float4 q0, q1;                                                          \
        ROWQ4(q0, (CUR)[0], (OLD)[0], hl0, hr0, hu1, hu2, (CUR)[1], hd1, ca0, ct0, cs0); \
        ROWQ4(q1, (CUR)[1], (OLD)[1], hl1, hr1, (CUR)[0], hu1, hd1, hd2, ca1, ct1, cs1); \
        if (src0) {                                /* source row at slot gr*2 */ \
            q0.x += (ls == 0) ? as : 0.0f;                                      \
            q0.y += (ls == 1) ? as : 0.0f;                                      \
            q0.z += (ls == 2) ? as : 0.0f;                                      \
            q0.w += (ls == 3) ? as : 0.0f;                                      \
        }                                                                       \
        if (src1) {                                /* source row at slot gr*2+1 */ \
            q1.x += (ls == 0) ? as : 0.0f;                                      \
            q1.y += (ls == 1) ? as : 0.0f;                                      \
            q1.z += (ls == 2) ? as : 0.0f;                                      \
            q1.w += (ls == 3) ? as : 0.0f;                                      \
        }                                                                       \
        if (grec) {                                /* receivers: global row 31 */ \
            const int ob = shot * 100000 + Ti * 100 + xr0;                      \
            if (xr0 >= 0  && xr0 <= 99) out[ob]     = q1.x;                     \
            if (xr0 >= -1 && xr0 <= 98) out[ob + 1] = q1.y;                     \
            if (xr0 >= -2 && xr0 <= 97) out[ob + 2] = q1.z;                     \
            if (xr0 >= -3 && xr0 <= 96) out[ob + 3] = q1.w;                     \
        }                                                                       \
        (OLD)[0] = q0; (OLD)[1] = q1;                                           \
        ST4(PW, pc0, q0);                                                       \
        ST4(PW, pc0 + SROW, q1);                                                \
    }                                                                           \
    __syncthreads();                        /* PW complete, PR reads done */    \
} while (0)

// Epoch exchange (RH=2). At entry p1 = pB regs (also in PsA), p0 = pA regs.
#define EXCHANGE(E) do {                                                        \
    const int par = (E) & 1;                                                    \
    if (act) {                                                                  \
        _Pragma("unroll")                                                       \
        for (int r = 0; r < RH; ++r) {                                          \
            int slot = gr * 2 + r;                                              \
            if (slot >= halo_top && slot < halo_top + int_n) {                  \
                int grow = base + slot;                                         \
                size_t b1 = ((size_t)(par*2+0)*10 + shot)*GSEG + (size_t)grow*80 + 2*qx; \
                size_t b0 = ((size_t)(par*2+1)*10 + shot)*GSEG + (size_t)grow*80 + 2*qx; \
                st_remote16(Gu + b1, pB[r]);                                    \
                st_remote16(Gu + b0, pA[r]);                                    \
            }                                                                   \
        }                                                                       \
    }                                                                           \
    __syncthreads();                        /* exports drained */               \
    if (tid == 0)                                                               \
        __hip_atomic_store(&flags[(shot << 3) + seg], (unsigned)(E) + 1u,       \
                           __ATOMIC_RELEASE, __HIP_MEMORY_SCOPE_AGENT);         \
    if (tid == 64 && seg > 0)                                                   \
        while (__hip_atomic_load(&flags[(shot << 3) + seg - 1], __ATOMIC_ACQUIRE,\
                                 __HIP_MEMORY_SCOPE_AGENT) <= (unsigned)(E)) {} \
    if (tid == 128 && seg < 7)                                                  \
        while (__hip_atomic_load(&flags[(shot << 3) + seg + 1], __ATOMIC_ACQUIRE,\
                                 __HIP_MEMORY_SCOPE_AGENT) <= (unsigned)(E)) {} \
    __syncthreads();                        /* neighbors' data ready */         \
    if (act) {                                                                  \
        _Pragma("unroll")                                                       \
        for (int r = 0; r < RH; ++r) {                                          \
            int slot = gr * 2 + r;                                              \
            if (slot < halo_top || slot >= halo_top + int_n) {                  \
                int grow = base + slot;                                         \
                size_t b1 = ((size_t)(par*2+0)*10 + shot)*GSEG + (size_t)grow*80 + 2*qx; \
                size_t b0 = ((size_t)(par*2+1)*10 + shot)*GSEG + (size_t)grow*80 + 2*qx; \
                float4 v1 = ld_remote16(Gu + b1);                               \
                float4 v0 = ld_remote16(Gu + b0);                               \
                pB[r] = v1;                                                     \
                pA[r] = v0;                                                     \
                ST4(PsA, pc0 + r * SROW, v1);                                   \
            }                                                                   \
        }                                                                       \
    }                                                                           \
    __syncthreads();                        /* imported PsA rows visible */     \
} while (0)

// ---------- main: 80 blocks = 10 shots x 8 z-segments, 1024 threads ----------
__global__ __launch_bounds__(1024, 4) void fwi_main(const float4* __restrict__ CST4,
                                                    const float* __restrict__ ws,
                                                    unsigned long long* __restrict__ Gu,
                                                    unsigned int* __restrict__ flags,
                                                    float* __restrict__ out) {
    __shared__ float PsA[PSZ];     // p1 mirror, even-T read buffer (34,944 B)
    __shared__ float PsB[PSZ];     // p1 mirror, odd-T read buffer (34,944 B)
    __shared__ float Wv[1024];     // wavelet, zero-padded
    const int tid = threadIdx.x;
    const int bid = blockIdx.x;
    const int shot = bid >> 3, seg = bid & 7;

    for (int i = tid; i < PSZ; i += 1024) { PsA[i] = 0.0f; PsB[i] = 0.0f; }
    Wv[tid] = (tid < 111) ? ws[tid] : 0.0f;

    const int int_base = 16 * seg;                 // interior global start row
    const int int_n = (seg < 7) ? 16 : 18;         // interior rows
    const int base = (seg > 0) ? int_base - 16 : 0;// stored global start row
    const int halo_top = (seg > 0) ? 16 : 0;
    const int stored_n = halo_top + int_n + ((seg < 7) ? 16 : 0); // 32|48|34 (even)
    const bool ct = (seg > 0);                     // top cut exists
    const bool cb = (seg < 7);                     // bottom cut exists
    const int ng = stored_n >> 1;                  // groups covering stored rows

    const int gr = tid / 40;                       // z-group 0..24 (RH=2 rows)
    const int qx = tid - gr * 40;                  // x-quad 0..39
    const bool act = (gr < 24) && (gr * 2 < stored_n);
    const float amp = ws[1000 + shot];
    const int xs = 30 + 11 * shot;
    const bool isq = (qx == (xs >> 2));
    const int ls = xs & 3;
    const int s31 = 31 - base;                     // stored slot of source row
    const bool src0 = act && isq && (gr * 2 == s31);
    const bool src1 = act && isq && (gr * 2 + 1 == s31);
    const int pc0 = (gr * 2 + 2) * SROW + 4 * qx + 4;
    const float4* cst = CST4 + (size_t)((base + gr * 2) * 40 + qx) * 3;
    const bool grec = (seg == 1) && (gr == 15);    // slot 31 = global row 31 (r=1)
    const int xr0 = 4 * qx - 30;                   // receiver index of lane j=0

    // hoisted time-invariant coefficients (24 VGPRs)
    float4 ca0, ct0, cs0, ca1, ct1, cs1;
    ca0 = ct0 = cs0 = ca1 = ct1 = cs1 = make_float4(0.f, 0.f, 0.f, 0.f);
    if (act) {
        ca0 = cst[0];   ct0 = cst[1];   cs0 = cst[2];
        ca1 = cst[120]; ct1 = cst[121]; cs1 = cst[122];
    }

    float4 pA[RH], pB[RH];                         // two generations in regs
    #pragma unroll
    for (int r = 0; r < RH; ++r) {
        pA[r] = make_float4(0.f, 0.f, 0.f, 0.f);
        pB[r] = make_float4(0.f, 0.f, 0.f, 0.f);
    }
    __syncthreads();

    for (int e = 0; e < 125; ++e) {                // 125 epochs x 8 sub-steps
        #pragma unroll
        for (int kk = 0; kk < 4; ++kk) {
            STEP(pB, pA, e * 8 + 2 * kk,     2 * kk,     PsA, PsB);
            STEP(pA, pB, e * 8 + 2 * kk + 1, 2 * kk + 1, PsB, PsA);
        }
        if (e < 124) EXCHANGE(e);
    }
}

extern "C" void kernel_launch(void* const* d_in, const int* in_sizes, int n_in,
                              void* d_out, int out_size, void* d_ws, size_t ws_size,
                              hipStream_t stream) {
    const float* v = (const float*)d_in[0];
    float* ws = (float*)d_ws;
    float* CST = (float*)((char*)d_ws + CST_OFF);
    unsigned long long* Gu = (unsigned long long*)((char*)d_ws + G_OFF);
    unsigned int* flags = (unsigned int*)((char*)d_ws + FLAG_OFF);
    float* out = (float*)d_out;

    fwi_setup1<<<1, 1024, 0, stream>>>(v, ws, flags);
    fwi_setup2<<<82, 256, 0, stream>>>(v, ws, CST);
    fwi_main<<<80, 1024, 0, stream>>>((const float4*)CST, ws, Gu, flags, out);
}